// Round 1
// baseline (982.759 us; speedup 1.0000x reference)
//
#include <hip/hip_runtime.h>

#define B_ 16
#define C_ 128
#define N_ 1024
#define K_ 9
#define NEG_SLOPE 0.2f
#define BN_EPS 1e-5f

__device__ __forceinline__ bool dless(float d1, int i1, float d2, int i2) {
    return (d1 < d2) || (d1 == d2 && i1 < i2);
}

__device__ __forceinline__ void insert9(float (&bd)[9], int (&bi)[9], float d, int m) {
    if (dless(d, m, bd[8], bi[8])) {
        bd[8] = d; bi[8] = m;
        #pragma unroll
        for (int q = 8; q > 0; --q) {
            if (dless(bd[q], bi[q], bd[q-1], bi[q-1])) {
                float td = bd[q]; bd[q] = bd[q-1]; bd[q-1] = td;
                int ti = bi[q]; bi[q] = bi[q-1]; bi[q-1] = ti;
            }
        }
    }
}

// ---------------------------------------------------------------- sq[b][n]
__global__ __launch_bounds__(256) void k_sq(const float* __restrict__ x,
                                            float* __restrict__ sq)
{
    int flat = blockIdx.x * 256 + threadIdx.x;     // 16384 = B*N
    int b = flat >> 10, n = flat & 1023;
    float acc = 0.f;
    for (int c = 0; c < C_; ++c) {
        float v = x[(b * C_ + c) * N_ + n];
        acc += v * v;
    }
    sq[flat] = acc;
}

// ------------------------------------------------- featsT[b][n][c] = x[b][c][n]
__global__ __launch_bounds__(256) void k_transpose(const float* __restrict__ x,
                                                   float* __restrict__ featsT)
{
    __shared__ float t[32][33];
    int blk = blockIdx.x;            // B * (C/32) * (N/32) = 16*4*32 = 2048
    int b = blk / 128;
    int rem = blk % 128;
    int c0 = (rem / 32) * 32;
    int n0 = (rem % 32) * 32;
    int tj = threadIdx.x & 31;
    int ti = threadIdx.x >> 5;       // 0..7
    #pragma unroll
    for (int s = 0; s < 32; s += 8) {
        int c = c0 + ti + s;
        t[ti + s][tj] = x[(b * C_ + c) * N_ + n0 + tj];
    }
    __syncthreads();
    #pragma unroll
    for (int s = 0; s < 32; s += 8) {
        int n = n0 + ti + s;
        featsT[(b * N_ + n) * C_ + c0 + tj] = t[tj][ti + s];
    }
}

// --------------------------------------- fused Gram row-tile + top-9 selection
// grid = B * (N/8) = 2048 blocks, 256 threads; 8 rows per block
__global__ __launch_bounds__(256) void k_knn(const float* __restrict__ x,
        const float* __restrict__ featsT, const float* __restrict__ sq,
        int* __restrict__ idxout)
{
    __shared__ float cenT[C_][8];        // 4 KB  [c][r]
    __shared__ float d2t[8][N_];         // 32 KB
    __shared__ float candD[8][32][9];    // 9 KB
    __shared__ int   candI[8][32][9];    // 9 KB
    __shared__ float sqn[8];

    int L = blockIdx.x;
    // XCD swizzle: keep 2 batches per XCD for L2 locality on x[b] slices
    int xcd = L & 7;
    int slot = L >> 3;                   // 0..255
    int b = xcd + 8 * (slot >> 7);
    int tile = slot & 127;
    int n0 = tile * 8;
    int tid = threadIdx.x;

    #pragma unroll
    for (int s = 0; s < 4; ++s) {
        int lin = s * 256 + tid;
        int r = lin >> 7, c = lin & 127;
        cenT[c][r] = featsT[(b * N_ + n0 + r) * C_ + c];
    }
    if (tid < 8) sqn[tid] = sq[b * N_ + n0 + tid];
    __syncthreads();

    float acc[8][4];
    #pragma unroll
    for (int r = 0; r < 8; ++r)
        #pragma unroll
        for (int mi = 0; mi < 4; ++mi) acc[r][mi] = 0.f;

    for (int c = 0; c < C_; ++c) {
        float xv[4];
        #pragma unroll
        for (int mi = 0; mi < 4; ++mi)
            xv[mi] = x[(b * C_ + c) * N_ + mi * 256 + tid];
        float cr[8];
        #pragma unroll
        for (int r = 0; r < 8; ++r) cr[r] = cenT[c][r];
        #pragma unroll
        for (int r = 0; r < 8; ++r)
            #pragma unroll
            for (int mi = 0; mi < 4; ++mi)
                acc[r][mi] += cr[r] * xv[mi];
    }
    #pragma unroll
    for (int mi = 0; mi < 4; ++mi) {
        float sm = sq[b * N_ + mi * 256 + tid];
        #pragma unroll
        for (int r = 0; r < 8; ++r)
            d2t[r][mi * 256 + tid] = sqn[r] + sm - 2.f * acc[r][mi];
    }
    __syncthreads();

    // per-thread local top-9 over 32 values (32 threads per row)
    int r = tid >> 5, s = tid & 31;
    float bd[9]; int bi[9];
    #pragma unroll
    for (int q = 0; q < 9; ++q) { bd[q] = 3.402823466e38f; bi[q] = 0x7fffffff; }
    for (int q = 0; q < 32; ++q) {
        int m = q * 32 + s;              // stride-32: conflict-free LDS
        insert9(bd, bi, d2t[r][m], m);
    }
    #pragma unroll
    for (int q = 0; q < 9; ++q) { candD[r][s][q] = bd[q]; candI[r][s][q] = bi[q]; }
    __syncthreads();

    if (tid < 8) {
        int rr = tid;
        float fd[9]; int fi[9];
        #pragma unroll
        for (int q = 0; q < 9; ++q) { fd[q] = 3.402823466e38f; fi[q] = 0x7fffffff; }
        for (int t = 0; t < 32; ++t)
            for (int q = 0; q < 9; ++q)
                insert9(fd, fi, candD[rr][t][q], candI[rr][t][q]);
        for (int q = 0; q < 9; ++q)
            idxout[(b * N_ + n0 + rr) * K_ + q] = fi[q];
    }
}

// ------------------------------------------------ edge-MLP + maxpool over K
// grid = B * (N/4) = 4096 blocks, 128 threads (thread = output channel)
__global__ __launch_bounds__(128) void k_edge(const float* __restrict__ featsT,
        const int* __restrict__ idx, const float* __restrict__ W1,
        const float* __restrict__ b1, const float* __restrict__ W2,
        const float* __restrict__ b2, float* __restrict__ msg)
{
    __shared__ float edgeT[256][36];     // 36 KB  [input dim i][pk]
    __shared__ float h1T[128][36];       // 18 KB
    __shared__ float cen[4][128];        // 2 KB
    __shared__ int nb[36];

    int L = blockIdx.x;
    int xcd = L & 7;
    int slot = L >> 3;                   // 0..511
    int b = xcd + 8 * (slot >> 8);
    int tile = slot & 255;
    int n0 = tile * 4;
    int tid = threadIdx.x;

    if (tid < 36) nb[tid] = idx[(b * N_ + n0 + tid / 9) * K_ + (tid % 9)];
    #pragma unroll
    for (int p = 0; p < 4; ++p)
        cen[p][tid] = featsT[(b * N_ + n0 + p) * C_ + tid];
    __syncthreads();

    for (int pk = 0; pk < 36; ++pk) {
        int p = pk / 9;
        float nv = featsT[(b * N_ + nb[pk]) * C_ + tid];
        float cv = cen[p][tid];
        edgeT[tid][pk] = cv;             // edge[0..127] = center
        edgeT[128 + tid][pk] = nv - cv;  // edge[128..255] = nbr - center
    }
    __syncthreads();

    float h1[36];
    float bias1 = b1[tid];
    #pragma unroll
    for (int pk = 0; pk < 36; ++pk) h1[pk] = bias1;
    #pragma unroll 4
    for (int i = 0; i < 256; ++i) {
        float w = W1[i * C_ + tid];
        const float4* row = reinterpret_cast<const float4*>(edgeT[i]);
        #pragma unroll
        for (int q = 0; q < 9; ++q) {
            float4 e = row[q];
            h1[q * 4 + 0] += e.x * w;
            h1[q * 4 + 1] += e.y * w;
            h1[q * 4 + 2] += e.z * w;
            h1[q * 4 + 3] += e.w * w;
        }
    }
    #pragma unroll
    for (int pk = 0; pk < 36; ++pk) {
        float v = h1[pk];
        h1T[tid][pk] = (v >= 0.f) ? v : NEG_SLOPE * v;   // leaky relu
    }
    __syncthreads();

    float h2[36];
    float bias2 = b2[tid];
    #pragma unroll
    for (int pk = 0; pk < 36; ++pk) h2[pk] = bias2;
    #pragma unroll 4
    for (int i = 0; i < 128; ++i) {
        float w = W2[i * C_ + tid];
        const float4* row = reinterpret_cast<const float4*>(h1T[i]);
        #pragma unroll
        for (int q = 0; q < 9; ++q) {
            float4 e = row[q];
            h2[q * 4 + 0] += e.x * w;
            h2[q * 4 + 1] += e.y * w;
            h2[q * 4 + 2] += e.z * w;
            h2[q * 4 + 3] += e.w * w;
        }
    }
    #pragma unroll
    for (int p = 0; p < 4; ++p) {
        float m = h2[p * 9];
        #pragma unroll
        for (int q = 1; q < 9; ++q) m = fmaxf(m, h2[p * 9 + q]);
        msg[(b * C_ + tid) * N_ + n0 + p] = m;   // msg layout (B,C,N)
    }
}

// ---------------------------------------------------- BN statistics per channel
__global__ __launch_bounds__(256) void k_bnstats(const float* __restrict__ msg,
        const float* __restrict__ gamma, const float* __restrict__ beta,
        float* __restrict__ scale, float* __restrict__ shift)
{
    int c = blockIdx.x, tid = threadIdx.x;
    float s = 0.f, ss = 0.f;
    for (int b = 0; b < B_; ++b) {
        const float* row = msg + (b * C_ + c) * N_;
        for (int j = tid; j < N_; j += 256) {
            float v = row[j];
            s += v; ss += v * v;
        }
    }
    __shared__ float rs[256], rss[256];
    rs[tid] = s; rss[tid] = ss;
    __syncthreads();
    for (int off = 128; off > 0; off >>= 1) {
        if (tid < off) { rs[tid] += rs[tid + off]; rss[tid] += rss[tid + off]; }
        __syncthreads();
    }
    if (tid == 0) {
        float mean = rs[0] / (float)(B_ * N_);
        float var = rss[0] / (float)(B_ * N_) - mean * mean;
        float inv = 1.0f / sqrtf(var + BN_EPS);
        float g = gamma[c];
        scale[c] = g * inv;
        shift[c] = beta[c] - g * inv * mean;
    }
}

// ------------------------------------------- BN apply + residual + final ReLU
__global__ __launch_bounds__(256) void k_final(const float* __restrict__ msg,
        const float* __restrict__ x, const float* __restrict__ scale,
        const float* __restrict__ shift, float* __restrict__ out)
{
    int i = blockIdx.x * 256 + threadIdx.x;      // float4 index, 524288 total
    int e = i << 2;
    int c = (e >> 10) & 127;
    float sc = scale[c], sh = shift[c];
    float4 m4 = reinterpret_cast<const float4*>(msg)[i];
    float4 x4 = reinterpret_cast<const float4*>(x)[i];
    float4 o;
    o.x = fmaxf(m4.x * sc + sh + x4.x, 0.f);
    o.y = fmaxf(m4.y * sc + sh + x4.y, 0.f);
    o.z = fmaxf(m4.z * sc + sh + x4.z, 0.f);
    o.w = fmaxf(m4.w * sc + sh + x4.w, 0.f);
    reinterpret_cast<float4*>(out)[i] = o;
}

extern "C" void kernel_launch(void* const* d_in, const int* in_sizes, int n_in,
                              void* d_out, int out_size, void* d_ws, size_t ws_size,
                              hipStream_t stream)
{
    const float* x     = (const float*)d_in[0];
    const float* W1    = (const float*)d_in[1];
    const float* b1    = (const float*)d_in[2];
    const float* W2    = (const float*)d_in[3];
    const float* b2    = (const float*)d_in[4];
    const float* gamma = (const float*)d_in[5];
    const float* beta  = (const float*)d_in[6];
    float* out = (float*)d_out;

    float* ws     = (float*)d_ws;
    float* featsT = ws;                     // 2097152 floats (8 MB)
    float* msg    = ws + 2097152;           // 2097152 floats (8 MB)
    float* sq     = ws + 4194304;           // 16384
    float* scale  = ws + 4210688;           // 128
    float* shift  = ws + 4210816;           // 128
    int*   idx    = (int*)(ws + 4210944);   // 147456 ints
    // total ~17.4 MB of d_ws

    k_sq       <<<  64, 256, 0, stream>>>(x, sq);
    k_transpose<<<2048, 256, 0, stream>>>(x, featsT);
    k_knn      <<<2048, 256, 0, stream>>>(x, featsT, sq, idx);
    k_edge     <<<4096, 128, 0, stream>>>(featsT, idx, W1, b1, W2, b2, msg);
    k_bnstats  <<< 128, 256, 0, stream>>>(msg, gamma, beta, scale, shift);
    k_final    <<<2048, 256, 0, stream>>>(msg, x, scale, shift, out);
}

// Round 2
// 461.997 us; speedup vs baseline: 2.1272x; 2.1272x over previous
//
#include <hip/hip_runtime.h>

#define B_ 16
#define C_ 128
#define N_ 1024
#define K_ 9
#define NEG_SLOPE 0.2f
#define BN_EPS 1e-5f
#define FLT_BIG 3.402823466e38f

// ---------------------------------------------------------------- sq[b][n]
__global__ __launch_bounds__(256) void k_sq(const float* __restrict__ x,
                                            float* __restrict__ sq)
{
    int flat = blockIdx.x * 256 + threadIdx.x;     // 16384 = B*N
    int b = flat >> 10, n = flat & 1023;
    float acc = 0.f;
    for (int c = 0; c < C_; ++c) {
        float v = x[(b * C_ + c) * N_ + n];
        acc += v * v;
    }
    sq[flat] = acc;
}

// ------------------------------------------------- featsT[b][n][c] = x[b][c][n]
__global__ __launch_bounds__(256) void k_transpose(const float* __restrict__ x,
                                                   float* __restrict__ featsT)
{
    __shared__ float t[32][33];
    int blk = blockIdx.x;            // B * (C/32) * (N/32) = 16*4*32 = 2048
    int b = blk / 128;
    int rem = blk % 128;
    int c0 = (rem / 32) * 32;
    int n0 = (rem % 32) * 32;
    int tj = threadIdx.x & 31;
    int ti = threadIdx.x >> 5;       // 0..7
    #pragma unroll
    for (int s = 0; s < 32; s += 8) {
        int c = c0 + ti + s;
        t[ti + s][tj] = x[(b * C_ + c) * N_ + n0 + tj];
    }
    __syncthreads();
    #pragma unroll
    for (int s = 0; s < 32; s += 8) {
        int n = n0 + ti + s;
        featsT[(b * N_ + n) * C_ + c0 + tj] = t[tj][ti + s];
    }
}

// --------------------------------------- fused Gram row-tile + top-9 selection
// grid = B * (N/4) = 4096 blocks, 256 threads = 4 waves; wave r handles row n0+r
__global__ __launch_bounds__(256) void k_knn(const float* __restrict__ x,
        const float* __restrict__ featsT, const float* __restrict__ sq,
        int* __restrict__ idxout)
{
    __shared__ float cenT[C_][4];        // 2 KB  [c][r], 16B rows -> b128 broadcast
    __shared__ float d2t[4][N_];         // 16 KB
    __shared__ float sqn[4];

    int L = blockIdx.x;
    // XCD swizzle: 2 batches per XCD for L2 locality on x[b] slices
    int xcd = L & 7;
    int slot = L >> 3;                   // 0..511
    int b = xcd + 8 * (slot >> 8);
    int tile = slot & 255;
    int n0 = tile * 4;
    int tid = threadIdx.x;

    #pragma unroll
    for (int s = 0; s < 2; ++s) {
        int lin = s * 256 + tid;         // 512 center elements
        int r = lin >> 7, c = lin & 127;
        cenT[c][r] = featsT[(b * N_ + n0 + r) * C_ + c];
    }
    if (tid < 4) sqn[tid] = sq[b * N_ + n0 + tid];
    __syncthreads();

    // Gram: thread covers columns m = tid*4 + k, k=0..3, for all 4 rows
    float acc[4][4];
    #pragma unroll
    for (int r = 0; r < 4; ++r)
        #pragma unroll
        for (int k = 0; k < 4; ++k) acc[r][k] = 0.f;

    const float4* x4 = reinterpret_cast<const float4*>(x);
    for (int c = 0; c < C_; ++c) {
        float4 xv = x4[(b * C_ + c) * (N_ / 4) + tid];
        float4 ce = *reinterpret_cast<const float4*>(cenT[c]);  // broadcast
        acc[0][0] += ce.x * xv.x; acc[0][1] += ce.x * xv.y;
        acc[0][2] += ce.x * xv.z; acc[0][3] += ce.x * xv.w;
        acc[1][0] += ce.y * xv.x; acc[1][1] += ce.y * xv.y;
        acc[1][2] += ce.y * xv.z; acc[1][3] += ce.y * xv.w;
        acc[2][0] += ce.z * xv.x; acc[2][1] += ce.z * xv.y;
        acc[2][2] += ce.z * xv.z; acc[2][3] += ce.z * xv.w;
        acc[3][0] += ce.w * xv.x; acc[3][1] += ce.w * xv.y;
        acc[3][2] += ce.w * xv.z; acc[3][3] += ce.w * xv.w;
    }
    float4 sm = reinterpret_cast<const float4*>(sq)[b * (N_ / 4) + tid];
    #pragma unroll
    for (int r = 0; r < 4; ++r) {
        float4 o;
        o.x = sqn[r] + sm.x - 2.f * acc[r][0];
        o.y = sqn[r] + sm.y - 2.f * acc[r][1];
        o.z = sqn[r] + sm.z - 2.f * acc[r][2];
        o.w = sqn[r] + sm.w - 2.f * acc[r][3];
        *reinterpret_cast<float4*>(&d2t[r][tid * 4]) = o;   // lanes consecutive: conflict-free
    }
    __syncthreads();

    // selection: wave w owns row w; lane holds 16 values at m = lane + 64*j
    int wave = tid >> 6, lane = tid & 63;
    float v[16];
    #pragma unroll
    for (int j = 0; j < 16; ++j)
        v[j] = d2t[wave][lane + 64 * j];   // 2 lanes/bank: free

    unsigned consumed = 0;
    for (int q = 0; q < K_; ++q) {
        // local argmin over 16 (branch-free, first-smallest-j wins ties -> smallest index)
        float bd = FLT_BIG; int bj = 0;
        #pragma unroll
        for (int j = 0; j < 16; ++j) {
            float d = ((consumed >> j) & 1u) ? FLT_BIG : v[j];
            if (d < bd) { bd = d; bj = j; }
        }
        int bi = lane + 64 * bj;
        // wave-wide lex argmin (d, idx)
        float d = bd; int i = bi;
        #pragma unroll
        for (int off = 32; off > 0; off >>= 1) {
            float od = __shfl_xor(d, off);
            int   oi = __shfl_xor(i, off);
            if (od < d || (od == d && oi < i)) { d = od; i = oi; }
        }
        if (i == bi) consumed |= 1u << bj;   // unique owner
        if (lane == 0)
            idxout[(b * N_ + n0 + wave) * K_ + q] = i;
    }
}

// ------------------------------------------------ edge-MLP + maxpool over K
// grid = B * (N/4) = 4096 blocks, 128 threads (thread = output channel)
__global__ __launch_bounds__(128) void k_edge(const float* __restrict__ featsT,
        const int* __restrict__ idx, const float* __restrict__ W1,
        const float* __restrict__ b1, const float* __restrict__ W2,
        const float* __restrict__ b2, float* __restrict__ msg)
{
    __shared__ float edgeT[256][36];     // 36 KB  [input dim i][pk]
    __shared__ float h1T[128][36];       // 18 KB
    __shared__ float cen[4][128];        // 2 KB
    __shared__ int nb[36];

    int L = blockIdx.x;
    int xcd = L & 7;
    int slot = L >> 3;                   // 0..511
    int b = xcd + 8 * (slot >> 8);
    int tile = slot & 255;
    int n0 = tile * 4;
    int tid = threadIdx.x;

    if (tid < 36) nb[tid] = idx[(b * N_ + n0 + tid / 9) * K_ + (tid % 9)];
    #pragma unroll
    for (int p = 0; p < 4; ++p)
        cen[p][tid] = featsT[(b * N_ + n0 + p) * C_ + tid];
    __syncthreads();

    for (int pk = 0; pk < 36; ++pk) {
        int p = pk / 9;
        float nv = featsT[(b * N_ + nb[pk]) * C_ + tid];
        float cv = cen[p][tid];
        edgeT[tid][pk] = cv;             // edge[0..127] = center
        edgeT[128 + tid][pk] = nv - cv;  // edge[128..255] = nbr - center
    }
    __syncthreads();

    float h1[36];
    float bias1 = b1[tid];
    #pragma unroll
    for (int pk = 0; pk < 36; ++pk) h1[pk] = bias1;
    #pragma unroll 4
    for (int i = 0; i < 256; ++i) {
        float w = W1[i * C_ + tid];
        const float4* row = reinterpret_cast<const float4*>(edgeT[i]);
        #pragma unroll
        for (int q = 0; q < 9; ++q) {
            float4 e = row[q];
            h1[q * 4 + 0] += e.x * w;
            h1[q * 4 + 1] += e.y * w;
            h1[q * 4 + 2] += e.z * w;
            h1[q * 4 + 3] += e.w * w;
        }
    }
    #pragma unroll
    for (int pk = 0; pk < 36; ++pk) {
        float v = h1[pk];
        h1T[tid][pk] = (v >= 0.f) ? v : NEG_SLOPE * v;   // leaky relu
    }
    __syncthreads();

    float h2[36];
    float bias2 = b2[tid];
    #pragma unroll
    for (int pk = 0; pk < 36; ++pk) h2[pk] = bias2;
    #pragma unroll 4
    for (int i = 0; i < 128; ++i) {
        float w = W2[i * C_ + tid];
        const float4* row = reinterpret_cast<const float4*>(h1T[i]);
        #pragma unroll
        for (int q = 0; q < 9; ++q) {
            float4 e = row[q];
            h2[q * 4 + 0] += e.x * w;
            h2[q * 4 + 1] += e.y * w;
            h2[q * 4 + 2] += e.z * w;
            h2[q * 4 + 3] += e.w * w;
        }
    }
    #pragma unroll
    for (int p = 0; p < 4; ++p) {
        float m = h2[p * 9];
        #pragma unroll
        for (int q = 1; q < 9; ++q) m = fmaxf(m, h2[p * 9 + q]);
        msg[(b * C_ + tid) * N_ + n0 + p] = m;   // msg layout (B,C,N)
    }
}

// ---------------------------------------------------- BN statistics per channel
__global__ __launch_bounds__(256) void k_bnstats(const float* __restrict__ msg,
        const float* __restrict__ gamma, const float* __restrict__ beta,
        float* __restrict__ scale, float* __restrict__ shift)
{
    int c = blockIdx.x, tid = threadIdx.x;
    float s = 0.f, ss = 0.f;
    for (int b = 0; b < B_; ++b) {
        const float* row = msg + (b * C_ + c) * N_;
        for (int j = tid; j < N_; j += 256) {
            float v = row[j];
            s += v; ss += v * v;
        }
    }
    __shared__ float rs[256], rss[256];
    rs[tid] = s; rss[tid] = ss;
    __syncthreads();
    for (int off = 128; off > 0; off >>= 1) {
        if (tid < off) { rs[tid] += rs[tid + off]; rss[tid] += rss[tid + off]; }
        __syncthreads();
    }
    if (tid == 0) {
        float mean = rs[0] / (float)(B_ * N_);
        float var = rss[0] / (float)(B_ * N_) - mean * mean;
        float inv = 1.0f / sqrtf(var + BN_EPS);
        float g = gamma[c];
        scale[c] = g * inv;
        shift[c] = beta[c] - g * inv * mean;
    }
}

// ------------------------------------------- BN apply + residual + final ReLU
__global__ __launch_bounds__(256) void k_final(const float* __restrict__ msg,
        const float* __restrict__ x, const float* __restrict__ scale,
        const float* __restrict__ shift, float* __restrict__ out)
{
    int i = blockIdx.x * 256 + threadIdx.x;      // float4 index, 524288 total
    int e = i << 2;
    int c = (e >> 10) & 127;
    float sc = scale[c], sh = shift[c];
    float4 m4 = reinterpret_cast<const float4*>(msg)[i];
    float4 x4 = reinterpret_cast<const float4*>(x)[i];
    float4 o;
    o.x = fmaxf(m4.x * sc + sh + x4.x, 0.f);
    o.y = fmaxf(m4.y * sc + sh + x4.y, 0.f);
    o.z = fmaxf(m4.z * sc + sh + x4.z, 0.f);
    o.w = fmaxf(m4.w * sc + sh + x4.w, 0.f);
    reinterpret_cast<float4*>(out)[i] = o;
}

extern "C" void kernel_launch(void* const* d_in, const int* in_sizes, int n_in,
                              void* d_out, int out_size, void* d_ws, size_t ws_size,
                              hipStream_t stream)
{
    const float* x     = (const float*)d_in[0];
    const float* W1    = (const float*)d_in[1];
    const float* b1    = (const float*)d_in[2];
    const float* W2    = (const float*)d_in[3];
    const float* b2    = (const float*)d_in[4];
    const float* gamma = (const float*)d_in[5];
    const float* beta  = (const float*)d_in[6];
    float* out = (float*)d_out;

    float* ws     = (float*)d_ws;
    float* featsT = ws;                     // 2097152 floats (8 MB)
    float* msg    = ws + 2097152;           // 2097152 floats (8 MB)
    float* sq     = ws + 4194304;           // 16384
    float* scale  = ws + 4210688;           // 128
    float* shift  = ws + 4210816;           // 128
    int*   idx    = (int*)(ws + 4210944);   // 147456 ints
    // total ~17.4 MB of d_ws

    k_sq       <<<  64, 256, 0, stream>>>(x, sq);
    k_transpose<<<2048, 256, 0, stream>>>(x, featsT);
    k_knn      <<<4096, 256, 0, stream>>>(x, featsT, sq, idx);
    k_edge     <<<4096, 128, 0, stream>>>(featsT, idx, W1, b1, W2, b2, msg);
    k_bnstats  <<< 128, 256, 0, stream>>>(msg, gamma, beta, scale, shift);
    k_final    <<<2048, 256, 0, stream>>>(msg, x, scale, shift, out);
}

// Round 3
// 233.126 us; speedup vs baseline: 4.2156x; 1.9818x over previous
//
#include <hip/hip_runtime.h>

#define B_ 16
#define C_ 128
#define N_ 1024
#define K_ 9
#define NEG_SLOPE 0.2f
#define BN_EPS 1e-5f
#define FLT_BIG 3.402823466e38f

typedef __attribute__((ext_vector_type(8))) short short8;
typedef __attribute__((ext_vector_type(4))) float f32x4;
typedef __attribute__((ext_vector_type(4))) unsigned short u16x4;

__device__ __forceinline__ unsigned short f2bf(float f) {
    union { float f; unsigned u; } v; v.f = f;
    unsigned r = v.u + 0x7fffu + ((v.u >> 16) & 1u);   // RNE
    return (unsigned short)(r >> 16);
}

// ---------------------------------------------------------------- sq[b][n]
__global__ __launch_bounds__(256) void k_sq(const float* __restrict__ x,
                                            float* __restrict__ sq)
{
    int flat = blockIdx.x * 256 + threadIdx.x;     // 16384 = B*N
    int b = flat >> 10, n = flat & 1023;
    float acc = 0.f;
    for (int c = 0; c < C_; ++c) {
        float v = x[(b * C_ + c) * N_ + n];
        acc += v * v;
    }
    sq[flat] = acc;
}

// ------------------------------------------------- featsT[b][n][c] = x[b][c][n]
__global__ __launch_bounds__(256) void k_transpose(const float* __restrict__ x,
                                                   float* __restrict__ featsT)
{
    __shared__ float t[32][33];
    int blk = blockIdx.x;            // B * (C/32) * (N/32) = 2048
    int b = blk / 128;
    int rem = blk % 128;
    int c0 = (rem / 32) * 32;
    int n0 = (rem % 32) * 32;
    int tj = threadIdx.x & 31;
    int ti = threadIdx.x >> 5;
    #pragma unroll
    for (int s = 0; s < 32; s += 8)
        t[ti + s][tj] = x[(b * C_ + c0 + ti + s) * N_ + n0 + tj];
    __syncthreads();
    #pragma unroll
    for (int s = 0; s < 32; s += 8)
        featsT[(b * N_ + n0 + ti + s) * C_ + c0 + tj] = t[tj][ti + s];
}

// --------------------------------------- fused Gram row-tile + top-9 selection
__global__ __launch_bounds__(256) void k_knn(const float* __restrict__ x,
        const float* __restrict__ featsT, const float* __restrict__ sq,
        int* __restrict__ idxout)
{
    __shared__ float cenT[C_][4];
    __shared__ float d2t[4][N_];
    __shared__ float sqn[4];

    int L = blockIdx.x;
    int xcd = L & 7;
    int slot = L >> 3;
    int b = xcd + 8 * (slot >> 8);
    int tile = slot & 255;
    int n0 = tile * 4;
    int tid = threadIdx.x;

    #pragma unroll
    for (int s = 0; s < 2; ++s) {
        int lin = s * 256 + tid;
        int r = lin >> 7, c = lin & 127;
        cenT[c][r] = featsT[(b * N_ + n0 + r) * C_ + c];
    }
    if (tid < 4) sqn[tid] = sq[b * N_ + n0 + tid];
    __syncthreads();

    float acc[4][4];
    #pragma unroll
    for (int r = 0; r < 4; ++r)
        #pragma unroll
        for (int k = 0; k < 4; ++k) acc[r][k] = 0.f;

    const float4* x4 = reinterpret_cast<const float4*>(x);
    for (int c = 0; c < C_; ++c) {
        float4 xv = x4[(b * C_ + c) * (N_ / 4) + tid];
        float4 ce = *reinterpret_cast<const float4*>(cenT[c]);
        acc[0][0] += ce.x * xv.x; acc[0][1] += ce.x * xv.y;
        acc[0][2] += ce.x * xv.z; acc[0][3] += ce.x * xv.w;
        acc[1][0] += ce.y * xv.x; acc[1][1] += ce.y * xv.y;
        acc[1][2] += ce.y * xv.z; acc[1][3] += ce.y * xv.w;
        acc[2][0] += ce.z * xv.x; acc[2][1] += ce.z * xv.y;
        acc[2][2] += ce.z * xv.z; acc[2][3] += ce.z * xv.w;
        acc[3][0] += ce.w * xv.x; acc[3][1] += ce.w * xv.y;
        acc[3][2] += ce.w * xv.z; acc[3][3] += ce.w * xv.w;
    }
    float4 sm = reinterpret_cast<const float4*>(sq)[b * (N_ / 4) + tid];
    #pragma unroll
    for (int r = 0; r < 4; ++r) {
        float4 o;
        o.x = sqn[r] + sm.x - 2.f * acc[r][0];
        o.y = sqn[r] + sm.y - 2.f * acc[r][1];
        o.z = sqn[r] + sm.z - 2.f * acc[r][2];
        o.w = sqn[r] + sm.w - 2.f * acc[r][3];
        *reinterpret_cast<float4*>(&d2t[r][tid * 4]) = o;
    }
    __syncthreads();

    int wave = tid >> 6, lane = tid & 63;
    float v[16];
    #pragma unroll
    for (int j = 0; j < 16; ++j)
        v[j] = d2t[wave][lane + 64 * j];

    unsigned consumed = 0;
    for (int q = 0; q < K_; ++q) {
        float bd = FLT_BIG; int bj = 0;
        #pragma unroll
        for (int j = 0; j < 16; ++j) {
            float d = ((consumed >> j) & 1u) ? FLT_BIG : v[j];
            if (d < bd) { bd = d; bj = j; }
        }
        int bi = lane + 64 * bj;
        float d = bd; int i = bi;
        #pragma unroll
        for (int off = 32; off > 0; off >>= 1) {
            float od = __shfl_xor(d, off);
            int   oi = __shfl_xor(i, off);
            if (od < d || (od == d && oi < i)) { d = od; i = oi; }
        }
        if (i == bi) consumed |= 1u << bj;
        if (lane == 0)
            idxout[(b * N_ + n0 + wave) * K_ + q] = i;
    }
}

// ----------------------- prepack W1/W2 into MFMA B-fragment order (bf16)
// B-frag for 16x16x32: lane needs B[k = quad*8+j][n = 16w + (lane&15)], j=0..7
__global__ __launch_bounds__(256) void k_prepack(const float* __restrict__ W1,
        const float* __restrict__ W2, unsigned short* __restrict__ wf1,
        unsigned short* __restrict__ wf2)
{
    int t = blockIdx.x * 256 + threadIdx.x;       // 6144 threads
    if (t < 4096) {                               // W1: kk 0..7
        int kk = t >> 9, w = (t >> 6) & 7, lane = t & 63;
        int quad = lane >> 4, col = lane & 15;
        #pragma unroll
        for (int j = 0; j < 8; ++j)
            wf1[t * 8 + j] = f2bf(W1[(kk * 32 + quad * 8 + j) * C_ + 16 * w + col]);
    } else if (t < 6144) {                        // W2: kk 0..3
        int t2 = t - 4096;
        int kk = t2 >> 9, w = (t2 >> 6) & 7, lane = t2 & 63;
        int quad = lane >> 4, col = lane & 15;
        #pragma unroll
        for (int j = 0; j < 8; ++j)
            wf2[t2 * 8 + j] = f2bf(W2[(kk * 32 + quad * 8 + j) * C_ + 16 * w + col]);
    }
}

// ------------------- MFMA edge-MLP + maxpool: block = 16 points (144 edge rows)
// 512 threads = 8 waves; wave w owns output cols [16w,16w+16); 9 M-tiles of 16
__global__ __launch_bounds__(512, 1) void k_edge(const float* __restrict__ featsT,
        const int* __restrict__ idx, const unsigned short* __restrict__ wf1,
        const unsigned short* __restrict__ wf2, const float* __restrict__ b1,
        const float* __restrict__ b2, float* __restrict__ msg)
{
    // ed: [144][264] bf16 (76032 B); later aliased as h2 [144][132] fp32
    // h1: [144][136] bf16 (39168 B)
    __shared__ __align__(16) char smem[76032 + 39168];
    unsigned short* ed = (unsigned short*)smem;
    float*          h2 = (float*)smem;
    unsigned short* h1 = (unsigned short*)(smem + 76032);
    __shared__ int nb[144];

    int blk = blockIdx.x;                 // 1024 = 16 b * 64 tiles
    int b = blk >> 6;
    int n0 = (blk & 63) * 16;
    int tid = threadIdx.x;

    if (tid < 144) nb[tid] = idx[(b * N_ + n0 + tid / 9) * K_ + tid % 9];
    __syncthreads();

    // ---- build edge tile: group g (32 threads) handles point g
    {
        int g = tid >> 5, j = tid & 31;
        const float4* fT4 = (const float4*)featsT;
        float4 cv = fT4[(b * N_ + n0 + g) * 32 + j];
        u16x4 cb; cb.x = f2bf(cv.x); cb.y = f2bf(cv.y);
        cb.z = f2bf(cv.z); cb.w = f2bf(cv.w);
        #pragma unroll
        for (int q = 0; q < 9; ++q)
            *(u16x4*)&ed[(g * 9 + q) * 264 + 4 * j] = cb;
        #pragma unroll
        for (int q = 0; q < 9; ++q) {
            float4 nv = fT4[(b * N_ + nb[g * 9 + q]) * 32 + j];
            u16x4 db;
            db.x = f2bf(nv.x - cv.x); db.y = f2bf(nv.y - cv.y);
            db.z = f2bf(nv.z - cv.z); db.w = f2bf(nv.w - cv.w);
            *(u16x4*)&ed[(g * 9 + q) * 264 + 128 + 4 * j] = db;
        }
    }
    __syncthreads();

    int wv = tid >> 6;
    int lane = tid & 63;
    int quad = lane >> 4, col = lane & 15;

    // ---- GEMM1: edge[144x256] @ W1[256x128] + b1, leaky-ReLU -> h1 (bf16)
    float b1v = b1[16 * wv + col];
    f32x4 acc[9];
    #pragma unroll
    for (int t = 0; t < 9; ++t) acc[t] = (f32x4){b1v, b1v, b1v, b1v};

    const short8* w1f = (const short8*)wf1;
    #pragma unroll
    for (int kk = 0; kk < 8; ++kk) {
        short8 bf = w1f[(kk * 8 + wv) * 64 + lane];
        #pragma unroll
        for (int t = 0; t < 9; ++t) {
            short8 af = *(const short8*)&ed[(16 * t + col) * 264 + kk * 32 + quad * 8];
            acc[t] = __builtin_amdgcn_mfma_f32_16x16x32_bf16(af, bf, acc[t], 0, 0, 0);
        }
    }
    #pragma unroll
    for (int t = 0; t < 9; ++t)
        #pragma unroll
        for (int r = 0; r < 4; ++r) {
            float v = acc[t][r];
            v = (v >= 0.f) ? v : NEG_SLOPE * v;
            h1[(16 * t + quad * 4 + r) * 136 + 16 * wv + col] = f2bf(v);
        }
    __syncthreads();

    // ---- GEMM2: h1[144x128] @ W2[128x128] -> h2 (fp32, aliases ed)
    f32x4 acc2[9];
    #pragma unroll
    for (int t = 0; t < 9; ++t) acc2[t] = (f32x4){0.f, 0.f, 0.f, 0.f};

    const short8* w2f = (const short8*)wf2;
    #pragma unroll
    for (int kk = 0; kk < 4; ++kk) {
        short8 bf = w2f[(kk * 8 + wv) * 64 + lane];
        #pragma unroll
        for (int t = 0; t < 9; ++t) {
            short8 af = *(const short8*)&h1[(16 * t + col) * 136 + kk * 32 + quad * 8];
            acc2[t] = __builtin_amdgcn_mfma_f32_16x16x32_bf16(af, bf, acc2[t], 0, 0, 0);
        }
    }
    #pragma unroll
    for (int t = 0; t < 9; ++t)
        #pragma unroll
        for (int r = 0; r < 4; ++r)
            h2[(16 * t + quad * 4 + r) * 132 + 16 * wv + col] = acc2[t][r];
    __syncthreads();

    // ---- maxpool over 9 edges/point + bias, write msg (B,C,N)
    // lanes 0..15 = consecutive p -> 64B coalesced msg segments
    int p = tid & 15, nbase = tid >> 4;   // nbase 0..31
    #pragma unroll
    for (int it = 0; it < 4; ++it) {
        int n = nbase + 32 * it;
        float m = h2[(p * 9) * 132 + n];
        #pragma unroll
        for (int q = 1; q < 9; ++q)
            m = fmaxf(m, h2[(p * 9 + q) * 132 + n]);
        msg[(b * C_ + n) * N_ + n0 + p] = m + b2[n];
    }
}

// ---------------------------------------------------- BN statistics per channel
__global__ __launch_bounds__(256) void k_bnstats(const float* __restrict__ msg,
        const float* __restrict__ gamma, const float* __restrict__ beta,
        float* __restrict__ scale, float* __restrict__ shift)
{
    int c = blockIdx.x, tid = threadIdx.x;
    float s = 0.f, ss = 0.f;
    for (int b = 0; b < B_; ++b) {
        const float* row = msg + (b * C_ + c) * N_;
        for (int j = tid; j < N_; j += 256) {
            float v = row[j];
            s += v; ss += v * v;
        }
    }
    __shared__ float rs[256], rss[256];
    rs[tid] = s; rss[tid] = ss;
    __syncthreads();
    for (int off = 128; off > 0; off >>= 1) {
        if (tid < off) { rs[tid] += rs[tid + off]; rss[tid] += rss[tid + off]; }
        __syncthreads();
    }
    if (tid == 0) {
        float mean = rs[0] / (float)(B_ * N_);
        float var = rss[0] / (float)(B_ * N_) - mean * mean;
        float inv = 1.0f / sqrtf(var + BN_EPS);
        float g = gamma[c];
        scale[c] = g * inv;
        shift[c] = beta[c] - g * inv * mean;
    }
}

// ------------------------------------------- BN apply + residual + final ReLU
__global__ __launch_bounds__(256) void k_final(const float* __restrict__ msg,
        const float* __restrict__ x, const float* __restrict__ scale,
        const float* __restrict__ shift, float* __restrict__ out)
{
    int i = blockIdx.x * 256 + threadIdx.x;
    int e = i << 2;
    int c = (e >> 10) & 127;
    float sc = scale[c], sh = shift[c];
    float4 m4 = reinterpret_cast<const float4*>(msg)[i];
    float4 x4 = reinterpret_cast<const float4*>(x)[i];
    float4 o;
    o.x = fmaxf(m4.x * sc + sh + x4.x, 0.f);
    o.y = fmaxf(m4.y * sc + sh + x4.y, 0.f);
    o.z = fmaxf(m4.z * sc + sh + x4.z, 0.f);
    o.w = fmaxf(m4.w * sc + sh + x4.w, 0.f);
    reinterpret_cast<float4*>(out)[i] = o;
}

extern "C" void kernel_launch(void* const* d_in, const int* in_sizes, int n_in,
                              void* d_out, int out_size, void* d_ws, size_t ws_size,
                              hipStream_t stream)
{
    const float* x     = (const float*)d_in[0];
    const float* W1    = (const float*)d_in[1];
    const float* b1    = (const float*)d_in[2];
    const float* W2    = (const float*)d_in[3];
    const float* b2    = (const float*)d_in[4];
    const float* gamma = (const float*)d_in[5];
    const float* beta  = (const float*)d_in[6];
    float* out = (float*)d_out;

    float* ws     = (float*)d_ws;
    float* featsT = ws;                     // 2097152 floats (8 MB)
    float* msg    = ws + 2097152;           // 2097152 floats (8 MB)
    float* sq     = ws + 4194304;           // 16384
    float* scale  = ws + 4210688;           // 128
    float* shift  = ws + 4210816;           // 128
    int*   idx    = (int*)(ws + 4210944);   // 147456 ints
    unsigned short* wf1 = (unsigned short*)(ws + 4358400);  // 32768 bf16
    unsigned short* wf2 = (unsigned short*)(ws + 4374784);  // 16384 bf16
    // total ~17.5 MB of d_ws

    k_sq       <<<  64, 256, 0, stream>>>(x, sq);
    k_transpose<<<2048, 256, 0, stream>>>(x, featsT);
    k_prepack  <<<  24, 256, 0, stream>>>(W1, W2, wf1, wf2);
    k_knn      <<<4096, 256, 0, stream>>>(x, featsT, sq, idx);
    k_edge     <<<1024, 512, 0, stream>>>(featsT, idx, wf1, wf2, b1, b2, msg);
    k_bnstats  <<< 128, 256, 0, stream>>>(msg, gamma, beta, scale, shift);
    k_final    <<<2048, 256, 0, stream>>>(msg, x, scale, shift, out);
}

// Round 4
// 224.631 us; speedup vs baseline: 4.3750x; 1.0378x over previous
//
#include <hip/hip_runtime.h>

#define B_ 16
#define C_ 128
#define N_ 1024
#define K_ 9
#define NEG_SLOPE 0.2f
#define BN_EPS 1e-5f
#define FLT_BIG 3.402823466e38f

typedef __attribute__((ext_vector_type(8))) short short8;
typedef __attribute__((ext_vector_type(4))) float f32x4;
typedef __attribute__((ext_vector_type(4))) unsigned short u16x4;

__device__ __forceinline__ unsigned short f2bf(float f) {
    union { float f; unsigned u; } v; v.f = f;
    unsigned r = v.u + 0x7fffu + ((v.u >> 16) & 1u);   // RNE
    return (unsigned short)(r >> 16);
}
__device__ __forceinline__ float bf2f(unsigned short h) {
    union { unsigned u; float f; } v; v.u = ((unsigned)h) << 16; return v.f;
}

// ------------------------------------------------- featsT[b][n][c] = x[b][c][n]
__global__ __launch_bounds__(256) void k_transpose(const float* __restrict__ x,
                                                   float* __restrict__ featsT)
{
    __shared__ float t[32][33];
    int blk = blockIdx.x;            // B * (C/32) * (N/32) = 2048
    int b = blk / 128;
    int rem = blk % 128;
    int c0 = (rem / 32) * 32;
    int n0 = (rem % 32) * 32;
    int tj = threadIdx.x & 31;
    int ti = threadIdx.x >> 5;
    #pragma unroll
    for (int s = 0; s < 32; s += 8)
        t[ti + s][tj] = x[(b * C_ + c0 + ti + s) * N_ + n0 + tj];
    __syncthreads();
    #pragma unroll
    for (int s = 0; s < 32; s += 8)
        featsT[(b * N_ + n0 + ti + s) * C_ + c0 + tj] = t[tj][ti + s];
}

// ---------------- prep: Bf (B-frag hi/lo bf16 for KNN MFMA) + sq (fp32)
// block = 256 threads = 4 waves = 8 points; half-wave (32 lanes) per point
__global__ __launch_bounds__(256) void k_prep(const float* __restrict__ featsT,
        unsigned short* __restrict__ Bf, float* __restrict__ sq)
{
    int tid = threadIdx.x;
    int lane = tid & 63, wv = tid >> 6;
    int half = lane >> 5;                    // 0/1 within wave
    int l2 = lane & 31;
    int gp = blockIdx.x * 8 + wv * 2 + half; // global point
    int b = gp >> 10, n = gp & 1023;

    int ch0 = (l2 & 15) * 8;
    const float4* f4 = (const float4*)&featsT[gp * C_ + ch0];
    float4 v0 = f4[0], v1 = f4[1];

    u16x4 o0, o1;
    if (l2 < 16) {
        o0.x = f2bf(v0.x); o0.y = f2bf(v0.y); o0.z = f2bf(v0.z); o0.w = f2bf(v0.w);
        o1.x = f2bf(v1.x); o1.y = f2bf(v1.y); o1.z = f2bf(v1.z); o1.w = f2bf(v1.w);
    } else {
        o0.x = f2bf(v0.x - bf2f(f2bf(v0.x))); o0.y = f2bf(v0.y - bf2f(f2bf(v0.y)));
        o0.z = f2bf(v0.z - bf2f(f2bf(v0.z))); o0.w = f2bf(v0.w - bf2f(f2bf(v0.w)));
        o1.x = f2bf(v1.x - bf2f(f2bf(v1.x))); o1.y = f2bf(v1.y - bf2f(f2bf(v1.y)));
        o1.z = f2bf(v1.z - bf2f(f2bf(v1.z))); o1.w = f2bf(v1.w - bf2f(f2bf(v1.w)));
    }
    // chunk = ((b*8 + kb)*64 + tile)*64 + quad*16 + (n&15); kb=l2>>2, quad=l2&3
    long chunk = (((long)(b * 8 + (l2 >> 2)) * 64 + (n >> 4)) << 6) + ((l2 & 3) * 16 + (n & 15));
    *(u16x4*)&Bf[chunk * 8]     = o0;
    *(u16x4*)&Bf[chunk * 8 + 4] = o1;

    // sq: lanes l2<16 hold all 128 channels (8 each); lanes >=16 duplicate -> same sum
    float ss = v0.x*v0.x + v0.y*v0.y + v0.z*v0.z + v0.w*v0.w
             + v1.x*v1.x + v1.y*v1.y + v1.z*v1.z + v1.w*v1.w;
    #pragma unroll
    for (int off = 1; off < 16; off <<= 1)
        ss += __shfl_xor(ss, off);
    if (l2 == 0) sq[gp] = ss;
}

// --------------- MFMA KNN: block = 16 rows x 1024 cols, split-bf16 Gram + top-9
__global__ __launch_bounds__(512, 4) void k_knn(const float* __restrict__ featsT,
        const unsigned short* __restrict__ Bf, const float* __restrict__ sq,
        int* __restrict__ idxout)
{
    __shared__ unsigned short Ahl[16][264];   // [row][hi 0..127 | lo 128..255], pad
    __shared__ float sqs[N_];
    __shared__ float d2t[16][N_];             // score = sq[m] - 2*dot

    int L = blockIdx.x;                       // 1024 = 16 b * 64 tiles
    int xcd = L & 7, slot = L >> 3;           // XCD gets 2 consecutive batches
    int b = xcd * 2 + (slot >> 6);
    int tile = slot & 63;
    int n0 = tile * 16;
    int tid = threadIdx.x;

    sqs[tid] = sq[b * N_ + tid];
    sqs[tid + 512] = sq[b * N_ + tid + 512];
    {
        int row = tid >> 5, c4 = (tid & 31) * 4;
        float4 v = *(const float4*)&featsT[(b * N_ + n0 + row) * C_ + c4];
        u16x4 hi, lo;
        hi.x = f2bf(v.x); lo.x = f2bf(v.x - bf2f(hi.x));
        hi.y = f2bf(v.y); lo.y = f2bf(v.y - bf2f(hi.y));
        hi.z = f2bf(v.z); lo.z = f2bf(v.z - bf2f(hi.z));
        hi.w = f2bf(v.w); lo.w = f2bf(v.w - bf2f(hi.w));
        *(u16x4*)&Ahl[row][c4] = hi;
        *(u16x4*)&Ahl[row][128 + c4] = lo;
    }
    __syncthreads();

    int wv = tid >> 6, lane = tid & 63, quad = lane >> 4, cl = lane & 15;

    short8 af[8];
    #pragma unroll
    for (int ka = 0; ka < 8; ++ka)
        af[ka] = *(const short8*)&Ahl[cl][ka * 32 + quad * 8];

    f32x4 acc[8];
    #pragma unroll
    for (int t = 0; t < 8; ++t) acc[t] = (f32x4){0.f, 0.f, 0.f, 0.f};

    const short8* bfp = (const short8*)Bf;
    // 3 passes: hi*hi (s0..3), hiA*loB (s4..7), loA*hiB (s8..11)
    #pragma unroll
    for (int s = 0; s < 12; ++s) {
        int ka = (s < 4) ? s : s - 4;
        int kb = (s < 8) ? s : s - 8;
        long base = (((long)(b * 8 + kb) * 64 + wv * 8) << 6) + lane;
        #pragma unroll
        for (int t = 0; t < 8; ++t) {
            short8 bfr = bfp[base + t * 64];
            acc[t] = __builtin_amdgcn_mfma_f32_16x16x32_bf16(af[ka], bfr, acc[t], 0, 0, 0);
        }
    }
    #pragma unroll
    for (int t = 0; t < 8; ++t) {
        int col = ((wv * 8 + t) << 4) + cl;
        float sm = sqs[col];
        #pragma unroll
        for (int r = 0; r < 4; ++r)
            d2t[quad * 4 + r][col] = fmaf(-2.f, acc[t][r], sm);
    }
    __syncthreads();

    // top-9 per row: wave handles rows 2wv, 2wv+1; lazy local argmin + butterfly
    #pragma unroll 1
    for (int rr = 0; rr < 2; ++rr) {
        int row = wv * 2 + rr;
        float v[16];
        #pragma unroll
        for (int j = 0; j < 16; ++j)
            v[j] = d2t[row][lane + (j << 6)];
        float bd = v[0]; int bj = 0;
        #pragma unroll
        for (int j = 1; j < 16; ++j)
            if (v[j] < bd) { bd = v[j]; bj = j; }
        int bi = lane + (bj << 6);
        for (int q = 0; q < K_; ++q) {
            float d = bd; int i = bi;
            #pragma unroll
            for (int off = 32; off > 0; off >>= 1) {
                float od = __shfl_xor(d, off);
                int   oi = __shfl_xor(i, off);
                if (od < d || (od == d && oi < i)) { d = od; i = oi; }
            }
            if (lane == 0)
                idxout[(b * N_ + n0 + row) * K_ + q] = i;
            if (q < K_ - 1 && i == bi) {       // unique winner replaces + rescans
                v[bj] = FLT_BIG;
                bd = v[0]; bj = 0;
                #pragma unroll
                for (int j = 1; j < 16; ++j)
                    if (v[j] < bd) { bd = v[j]; bj = j; }
                bi = lane + (bj << 6);
            }
        }
    }
}

// ----------------------- prepack W1/W2 into MFMA B-fragment order (bf16)
__global__ __launch_bounds__(256) void k_prepack(const float* __restrict__ W1,
        const float* __restrict__ W2, unsigned short* __restrict__ wf1,
        unsigned short* __restrict__ wf2)
{
    int t = blockIdx.x * 256 + threadIdx.x;       // 6144 threads
    if (t < 4096) {                               // W1: kk 0..7
        int kk = t >> 9, w = (t >> 6) & 7, lane = t & 63;
        int quad = lane >> 4, col = lane & 15;
        #pragma unroll
        for (int j = 0; j < 8; ++j)
            wf1[t * 8 + j] = f2bf(W1[(kk * 32 + quad * 8 + j) * C_ + 16 * w + col]);
    } else if (t < 6144) {                        // W2: kk 0..3
        int t2 = t - 4096;
        int kk = t2 >> 9, w = (t2 >> 6) & 7, lane = t2 & 63;
        int quad = lane >> 4, col = lane & 15;
        #pragma unroll
        for (int j = 0; j < 8; ++j)
            wf2[t2 * 8 + j] = f2bf(W2[(kk * 32 + quad * 8 + j) * C_ + 16 * w + col]);
    }
}

// ------------------- MFMA edge-MLP + maxpool: block = 16 points (144 edge rows)
__global__ __launch_bounds__(512, 1) void k_edge(const float* __restrict__ featsT,
        const int* __restrict__ idx, const unsigned short* __restrict__ wf1,
        const unsigned short* __restrict__ wf2, const float* __restrict__ b1,
        const float* __restrict__ b2, float* __restrict__ msg)
{
    __shared__ __align__(16) char smem[76032 + 39168];
    unsigned short* ed = (unsigned short*)smem;     // [144][264] bf16
    float*          h2 = (float*)smem;              // [144][132] fp32 (aliases ed)
    unsigned short* h1 = (unsigned short*)(smem + 76032);  // [144][136] bf16
    __shared__ int nb[144];

    int blk = blockIdx.x;                 // 1024 = 16 b * 64 tiles
    int b = blk >> 6;
    int n0 = (blk & 63) * 16;
    int tid = threadIdx.x;

    if (tid < 144) nb[tid] = idx[(b * N_ + n0 + tid / 9) * K_ + tid % 9];
    __syncthreads();

    {
        int g = tid >> 5, j = tid & 31;
        const float4* fT4 = (const float4*)featsT;
        float4 cv = fT4[(b * N_ + n0 + g) * 32 + j];
        u16x4 cb; cb.x = f2bf(cv.x); cb.y = f2bf(cv.y);
        cb.z = f2bf(cv.z); cb.w = f2bf(cv.w);
        #pragma unroll
        for (int q = 0; q < 9; ++q)
            *(u16x4*)&ed[(g * 9 + q) * 264 + 4 * j] = cb;
        #pragma unroll
        for (int q = 0; q < 9; ++q) {
            float4 nv = fT4[(b * N_ + nb[g * 9 + q]) * 32 + j];
            u16x4 db;
            db.x = f2bf(nv.x - cv.x); db.y = f2bf(nv.y - cv.y);
            db.z = f2bf(nv.z - cv.z); db.w = f2bf(nv.w - cv.w);
            *(u16x4*)&ed[(g * 9 + q) * 264 + 128 + 4 * j] = db;
        }
    }
    __syncthreads();

    int wv = tid >> 6;
    int lane = tid & 63;
    int quad = lane >> 4, col = lane & 15;

    float b1v = b1[16 * wv + col];
    f32x4 acc[9];
    #pragma unroll
    for (int t = 0; t < 9; ++t) acc[t] = (f32x4){b1v, b1v, b1v, b1v};

    const short8* w1f = (const short8*)wf1;
    #pragma unroll
    for (int kk = 0; kk < 8; ++kk) {
        short8 bf = w1f[(kk * 8 + wv) * 64 + lane];
        #pragma unroll
        for (int t = 0; t < 9; ++t) {
            short8 af = *(const short8*)&ed[(16 * t + col) * 264 + kk * 32 + quad * 8];
            acc[t] = __builtin_amdgcn_mfma_f32_16x16x32_bf16(af, bf, acc[t], 0, 0, 0);
        }
    }
    #pragma unroll
    for (int t = 0; t < 9; ++t)
        #pragma unroll
        for (int r = 0; r < 4; ++r) {
            float v = acc[t][r];
            v = (v >= 0.f) ? v : NEG_SLOPE * v;
            h1[(16 * t + quad * 4 + r) * 136 + 16 * wv + col] = f2bf(v);
        }
    __syncthreads();

    f32x4 acc2[9];
    #pragma unroll
    for (int t = 0; t < 9; ++t) acc2[t] = (f32x4){0.f, 0.f, 0.f, 0.f};

    const short8* w2f = (const short8*)wf2;
    #pragma unroll
    for (int kk = 0; kk < 4; ++kk) {
        short8 bf = w2f[(kk * 8 + wv) * 64 + lane];
        #pragma unroll
        for (int t = 0; t < 9; ++t) {
            short8 af = *(const short8*)&h1[(16 * t + col) * 136 + kk * 32 + quad * 8];
            acc2[t] = __builtin_amdgcn_mfma_f32_16x16x32_bf16(af, bf, acc2[t], 0, 0, 0);
        }
    }
    #pragma unroll
    for (int t = 0; t < 9; ++t)
        #pragma unroll
        for (int r = 0; r < 4; ++r)
            h2[(16 * t + quad * 4 + r) * 132 + 16 * wv + col] = acc2[t][r];
    __syncthreads();

    int p = tid & 15, nbase = tid >> 4;
    #pragma unroll
    for (int it = 0; it < 4; ++it) {
        int n = nbase + 32 * it;
        float m = h2[(p * 9) * 132 + n];
        #pragma unroll
        for (int q = 1; q < 9; ++q)
            m = fmaxf(m, h2[(p * 9 + q) * 132 + n]);
        msg[(b * C_ + n) * N_ + n0 + p] = m + b2[n];
    }
}

// ---------------------------------------------------- BN statistics per channel
__global__ __launch_bounds__(256) void k_bnstats(const float* __restrict__ msg,
        const float* __restrict__ gamma, const float* __restrict__ beta,
        float* __restrict__ scale, float* __restrict__ shift)
{
    int c = blockIdx.x, tid = threadIdx.x;
    float s = 0.f, ss = 0.f;
    for (int b = 0; b < B_; ++b) {
        const float* row = msg + (b * C_ + c) * N_;
        for (int j = tid; j < N_; j += 256) {
            float v = row[j];
            s += v; ss += v * v;
        }
    }
    __shared__ float rs[256], rss[256];
    rs[tid] = s; rss[tid] = ss;
    __syncthreads();
    for (int off = 128; off > 0; off >>= 1) {
        if (tid < off) { rs[tid] += rs[tid + off]; rss[tid] += rss[tid + off]; }
        __syncthreads();
    }
    if (tid == 0) {
        float mean = rs[0] / (float)(B_ * N_);
        float var = rss[0] / (float)(B_ * N_) - mean * mean;
        float inv = 1.0f / sqrtf(var + BN_EPS);
        float g = gamma[c];
        scale[c] = g * inv;
        shift[c] = beta[c] - g * inv * mean;
    }
}

// ------------------------------------------- BN apply + residual + final ReLU
__global__ __launch_bounds__(256) void k_final(const float* __restrict__ msg,
        const float* __restrict__ x, const float* __restrict__ scale,
        const float* __restrict__ shift, float* __restrict__ out)
{
    int i = blockIdx.x * 256 + threadIdx.x;
    int e = i << 2;
    int c = (e >> 10) & 127;
    float sc = scale[c], sh = shift[c];
    float4 m4 = reinterpret_cast<const float4*>(msg)[i];
    float4 x4 = reinterpret_cast<const float4*>(x)[i];
    float4 o;
    o.x = fmaxf(m4.x * sc + sh + x4.x, 0.f);
    o.y = fmaxf(m4.y * sc + sh + x4.y, 0.f);
    o.z = fmaxf(m4.z * sc + sh + x4.z, 0.f);
    o.w = fmaxf(m4.w * sc + sh + x4.w, 0.f);
    reinterpret_cast<float4*>(out)[i] = o;
}

extern "C" void kernel_launch(void* const* d_in, const int* in_sizes, int n_in,
                              void* d_out, int out_size, void* d_ws, size_t ws_size,
                              hipStream_t stream)
{
    const float* x     = (const float*)d_in[0];
    const float* W1    = (const float*)d_in[1];
    const float* b1    = (const float*)d_in[2];
    const float* W2    = (const float*)d_in[3];
    const float* b2    = (const float*)d_in[4];
    const float* gamma = (const float*)d_in[5];
    const float* beta  = (const float*)d_in[6];
    float* out = (float*)d_out;

    float* ws     = (float*)d_ws;
    float* featsT = ws;                     // 8 MB
    float* msg    = ws + 2097152;           // 8 MB; Bf aliases (dead before k_edge)
    unsigned short* Bf = (unsigned short*)(ws + 2097152);
    float* sq     = ws + 4194304;           // 16384
    float* scale  = ws + 4210688;           // 128
    float* shift  = ws + 4210816;           // 128
    int*   idx    = (int*)(ws + 4210944);   // 147456 ints
    unsigned short* wf1 = (unsigned short*)(ws + 4358400);  // 32768 bf16
    unsigned short* wf2 = (unsigned short*)(ws + 4374784);  // 16384 bf16

    k_transpose<<<2048, 256, 0, stream>>>(x, featsT);
    k_prep     <<<2048, 256, 0, stream>>>(featsT, Bf, sq);
    k_prepack  <<<  24, 256, 0, stream>>>(W1, W2, wf1, wf2);
    k_knn      <<<1024, 512, 0, stream>>>(featsT, Bf, sq, idx);
    k_edge     <<<1024, 512, 0, stream>>>(featsT, idx, wf1, wf2, b1, b2, msg);
    k_bnstats  <<< 128, 256, 0, stream>>>(msg, gamma, beta, scale, shift);
    k_final    <<<2048, 256, 0, stream>>>(msg, x, scale, shift, out);
}

// Round 5
// 216.686 us; speedup vs baseline: 4.5354x; 1.0367x over previous
//
#include <hip/hip_runtime.h>

#define B_ 16
#define C_ 128
#define N_ 1024
#define K_ 9
#define NEG_SLOPE 0.2f
#define BN_EPS 1e-5f
#define FLT_BIG 3.402823466e38f

typedef __attribute__((ext_vector_type(8))) short short8;
typedef __attribute__((ext_vector_type(4))) float f32x4;
typedef __attribute__((ext_vector_type(4))) unsigned short u16x4;

__device__ __forceinline__ unsigned short f2bf(float f) {
    union { float f; unsigned u; } v; v.f = f;
    unsigned r = v.u + 0x7fffu + ((v.u >> 16) & 1u);   // RNE
    return (unsigned short)(r >> 16);
}
__device__ __forceinline__ float bf2f(unsigned short h) {
    union { unsigned u; float f; } v; v.u = ((unsigned)h) << 16; return v.f;
}

// ------------------------------------------------- featsT[b][n][c] = x[b][c][n]
__global__ __launch_bounds__(256) void k_transpose(const float* __restrict__ x,
                                                   float* __restrict__ featsT)
{
    __shared__ float t[32][33];
    int blk = blockIdx.x;            // B * (C/32) * (N/32) = 2048
    int b = blk / 128;
    int rem = blk % 128;
    int c0 = (rem / 32) * 32;
    int n0 = (rem % 32) * 32;
    int tj = threadIdx.x & 31;
    int ti = threadIdx.x >> 5;
    #pragma unroll
    for (int s = 0; s < 32; s += 8)
        t[ti + s][tj] = x[(b * C_ + c0 + ti + s) * N_ + n0 + tj];
    __syncthreads();
    #pragma unroll
    for (int s = 0; s < 32; s += 8)
        featsT[(b * N_ + n0 + ti + s) * C_ + c0 + tj] = t[tj][ti + s];
}

// ---------------- prep: Bf (B-frag hi/lo bf16 for KNN MFMA) + sq (fp32)
__global__ __launch_bounds__(256) void k_prep(const float* __restrict__ featsT,
        unsigned short* __restrict__ Bf, float* __restrict__ sq)
{
    int tid = threadIdx.x;
    int lane = tid & 63, wv = tid >> 6;
    int half = lane >> 5;
    int l2 = lane & 31;
    int gp = blockIdx.x * 8 + wv * 2 + half; // global point
    int b = gp >> 10, n = gp & 1023;

    int ch0 = (l2 & 15) * 8;
    const float4* f4 = (const float4*)&featsT[gp * C_ + ch0];
    float4 v0 = f4[0], v1 = f4[1];

    u16x4 o0, o1;
    if (l2 < 16) {
        o0.x = f2bf(v0.x); o0.y = f2bf(v0.y); o0.z = f2bf(v0.z); o0.w = f2bf(v0.w);
        o1.x = f2bf(v1.x); o1.y = f2bf(v1.y); o1.z = f2bf(v1.z); o1.w = f2bf(v1.w);
    } else {
        o0.x = f2bf(v0.x - bf2f(f2bf(v0.x))); o0.y = f2bf(v0.y - bf2f(f2bf(v0.y)));
        o0.z = f2bf(v0.z - bf2f(f2bf(v0.z))); o0.w = f2bf(v0.w - bf2f(f2bf(v0.w)));
        o1.x = f2bf(v1.x - bf2f(f2bf(v1.x))); o1.y = f2bf(v1.y - bf2f(f2bf(v1.y)));
        o1.z = f2bf(v1.z - bf2f(f2bf(v1.z))); o1.w = f2bf(v1.w - bf2f(f2bf(v1.w)));
    }
    // chunk = ((b*8 + kb)*64 + tile)*64 + quad*16 + (n&15); kb 0..3 hi, 4..7 lo
    long chunk = (((long)(b * 8 + (l2 >> 2)) * 64 + (n >> 4)) << 6) + ((l2 & 3) * 16 + (n & 15));
    *(u16x4*)&Bf[chunk * 8]     = o0;
    *(u16x4*)&Bf[chunk * 8 + 4] = o1;

    float ss = v0.x*v0.x + v0.y*v0.y + v0.z*v0.z + v0.w*v0.w
             + v1.x*v1.x + v1.y*v1.y + v1.z*v1.z + v1.w*v1.w;
    #pragma unroll
    for (int off = 1; off < 16; off <<= 1)
        ss += __shfl_xor(ss, off);
    if (l2 == 0) sq[gp] = ss;
}

// --------------- MFMA KNN: 16 rows x 1024 cols; selection in C-register layout
__global__ __launch_bounds__(512, 2) void k_knn(const float* __restrict__ featsT,
        const unsigned short* __restrict__ Bf, const float* __restrict__ sq,
        int* __restrict__ idxout)
{
    __shared__ unsigned short Ahl[16][264];   // [row][hi 0..127 | lo 128..255]
    __shared__ float2 cand[16][8][9];         // per-row per-wave top-9 (d, idx)

    int L = blockIdx.x;                       // 1024 = 16 b * 64 tiles
    int xcd = L & 7, slot = L >> 3;
    int b = xcd * 2 + (slot >> 6);
    int tile = slot & 63;
    int n0 = tile * 16;
    int tid = threadIdx.x;

    {   // stage A tile, split hi/lo
        int row = tid >> 5, c4 = (tid & 31) * 4;
        float4 v = *(const float4*)&featsT[(b * N_ + n0 + row) * C_ + c4];
        u16x4 hi, lo;
        hi.x = f2bf(v.x); lo.x = f2bf(v.x - bf2f(hi.x));
        hi.y = f2bf(v.y); lo.y = f2bf(v.y - bf2f(hi.y));
        hi.z = f2bf(v.z); lo.z = f2bf(v.z - bf2f(hi.z));
        hi.w = f2bf(v.w); lo.w = f2bf(v.w - bf2f(hi.w));
        *(u16x4*)&Ahl[row][c4] = hi;
        *(u16x4*)&Ahl[row][128 + c4] = lo;
    }
    __syncthreads();

    int wv = tid >> 6, lane = tid & 63, quad = lane >> 4, cl = lane & 15;

    f32x4 acc[8];
    #pragma unroll
    for (int t = 0; t < 8; ++t) acc[t] = (f32x4){0.f, 0.f, 0.f, 0.f};

    const short8* bfp = (const short8*)Bf;
    // B-hi passes: each B chunk feeds hiA*hiB and loA*hiB (read B once)
    #pragma unroll
    for (int kb = 0; kb < 4; ++kb) {
        short8 afh = *(const short8*)&Ahl[cl][kb * 32 + quad * 8];
        short8 afl = *(const short8*)&Ahl[cl][128 + kb * 32 + quad * 8];
        long base = (((long)(b * 8 + kb) * 64 + wv * 8) << 6) + lane;
        #pragma unroll
        for (int t = 0; t < 8; ++t) {
            short8 bfr = bfp[base + t * 64];
            acc[t] = __builtin_amdgcn_mfma_f32_16x16x32_bf16(afh, bfr, acc[t], 0, 0, 0);
            acc[t] = __builtin_amdgcn_mfma_f32_16x16x32_bf16(afl, bfr, acc[t], 0, 0, 0);
        }
    }
    // B-lo passes: hiA*loB
    #pragma unroll
    for (int kb = 4; kb < 8; ++kb) {
        short8 afh = *(const short8*)&Ahl[cl][(kb - 4) * 32 + quad * 8];
        long base = (((long)(b * 8 + kb) * 64 + wv * 8) << 6) + lane;
        #pragma unroll
        for (int t = 0; t < 8; ++t) {
            short8 bfr = bfp[base + t * 64];
            acc[t] = __builtin_amdgcn_mfma_f32_16x16x32_bf16(afh, bfr, acc[t], 0, 0, 0);
        }
    }

    // score = sq[m] - 2*dot (row-constant sq[n] dropped: rank-invariant)
    #pragma unroll
    for (int t = 0; t < 8; ++t) {
        float sm = sq[b * N_ + ((wv * 8 + t) << 4) + cl];
        #pragma unroll
        for (int r = 0; r < 4; ++r)
            acc[t][r] = fmaf(-2.f, acc[t][r], sm);
    }

    // per-wave top-9: 16-lane group (fixed quad) owns rows quad*4+r
    #pragma unroll 1
    for (int r = 0; r < 4; ++r) {
        unsigned cons = 0;
        float bd = FLT_BIG; int bt = 0;
        #pragma unroll
        for (int t = 0; t < 8; ++t)
            if (acc[t][r] < bd) { bd = acc[t][r]; bt = t; }
        int bi = ((wv * 8 + bt) << 4) + cl;
        #pragma unroll 1
        for (int q = 0; q < K_; ++q) {
            float d = bd; int i = bi;
            #pragma unroll
            for (int off = 1; off < 16; off <<= 1) {
                float od = __shfl_xor(d, off);
                int   oi = __shfl_xor(i, off);
                if (od < d || (od == d && oi < i)) { d = od; i = oi; }
            }
            if (cl == 0)
                cand[quad * 4 + r][wv][q] = make_float2(d, __int_as_float(i));
            if (q < K_ - 1 && i == bi) {       // unique winner: mask + rescan
                cons |= 1u << bt;
                bd = FLT_BIG; bt = 0;
                #pragma unroll
                for (int t = 0; t < 8; ++t) {
                    float dd = ((cons >> t) & 1u) ? FLT_BIG : acc[t][r];
                    if (dd < bd) { bd = dd; bt = t; }
                }
                bi = ((wv * 8 + bt) << 4) + cl;
            }
        }
    }
    __syncthreads();

    // merge 72 candidates -> top-9; wave wv owns rows 2wv, 2wv+1
    #pragma unroll 1
    for (int rr = 0; rr < 2; ++rr) {
        int row = wv * 2 + rr;
        const float2* cp = &cand[row][0][0];       // 72 entries
        float2 c0 = cp[lane];
        float d0 = c0.x; int i0 = __float_as_int(c0.y);
        float d1 = FLT_BIG; int i1 = 0x7fffffff;
        if (lane < 8) {
            float2 c1 = cp[64 + lane];
            d1 = c1.x; i1 = __float_as_int(c1.y);
        }
        bool s0 = (d0 < d1) || (d0 == d1 && i0 < i1);
        float bd = s0 ? d0 : d1; int bi = s0 ? i0 : i1;
        #pragma unroll 1
        for (int q = 0; q < K_; ++q) {
            float d = bd; int i = bi;
            #pragma unroll
            for (int off = 32; off > 0; off >>= 1) {
                float od = __shfl_xor(d, off);
                int   oi = __shfl_xor(i, off);
                if (od < d || (od == d && oi < i)) { d = od; i = oi; }
            }
            if (lane == 0)
                idxout[(b * N_ + n0 + row) * K_ + q] = i;
            if (q < K_ - 1) {
                if (i == i0) d0 = FLT_BIG;
                if (i == i1) d1 = FLT_BIG;
                bool t0 = (d0 < d1) || (d0 == d1 && i0 < i1);
                bd = t0 ? d0 : d1; bi = t0 ? i0 : i1;
            }
        }
    }
}

// ----------------------- prepack W1/W2 into MFMA B-fragment order (bf16)
__global__ __launch_bounds__(256) void k_prepack(const float* __restrict__ W1,
        const float* __restrict__ W2, unsigned short* __restrict__ wf1,
        unsigned short* __restrict__ wf2)
{
    int t = blockIdx.x * 256 + threadIdx.x;       // 6144 threads
    if (t < 4096) {                               // W1: kk 0..7
        int kk = t >> 9, w = (t >> 6) & 7, lane = t & 63;
        int quad = lane >> 4, col = lane & 15;
        #pragma unroll
        for (int j = 0; j < 8; ++j)
            wf1[t * 8 + j] = f2bf(W1[(kk * 32 + quad * 8 + j) * C_ + 16 * w + col]);
    } else if (t < 6144) {                        // W2: kk 0..3
        int t2 = t - 4096;
        int kk = t2 >> 9, w = (t2 >> 6) & 7, lane = t2 & 63;
        int quad = lane >> 4, col = lane & 15;
        #pragma unroll
        for (int j = 0; j < 8; ++j)
            wf2[t2 * 8 + j] = f2bf(W2[(kk * 32 + quad * 8 + j) * C_ + 16 * w + col]);
    }
}

// ------------------- MFMA edge-MLP + maxpool: block = 16 points (144 edge rows)
__global__ __launch_bounds__(512, 1) void k_edge(const float* __restrict__ featsT,
        const int* __restrict__ idx, const unsigned short* __restrict__ wf1,
        const unsigned short* __restrict__ wf2, const float* __restrict__ b1,
        const float* __restrict__ b2, float* __restrict__ msg)
{
    __shared__ __align__(16) char smem[76032 + 39168];
    unsigned short* ed = (unsigned short*)smem;     // [144][264] bf16
    float*          h2 = (float*)smem;              // [144][132] fp32 (aliases ed)
    unsigned short* h1 = (unsigned short*)(smem + 76032);  // [144][136] bf16
    __shared__ int nb[144];

    int blk = blockIdx.x;                 // 1024 = 16 b * 64 tiles
    int b = blk >> 6;
    int n0 = (blk & 63) * 16;
    int tid = threadIdx.x;

    if (tid < 144) nb[tid] = idx[(b * N_ + n0 + tid / 9) * K_ + tid % 9];
    __syncthreads();

    {
        int g = tid >> 5, j = tid & 31;
        const float4* fT4 = (const float4*)featsT;
        float4 cv = fT4[(b * N_ + n0 + g) * 32 + j];
        u16x4 cb; cb.x = f2bf(cv.x); cb.y = f2bf(cv.y);
        cb.z = f2bf(cv.z); cb.w = f2bf(cv.w);
        #pragma unroll
        for (int q = 0; q < 9; ++q)
            *(u16x4*)&ed[(g * 9 + q) * 264 + 4 * j] = cb;
        #pragma unroll
        for (int q = 0; q < 9; ++q) {
            float4 nv = fT4[(b * N_ + nb[g * 9 + q]) * 32 + j];
            u16x4 db;
            db.x = f2bf(nv.x - cv.x); db.y = f2bf(nv.y - cv.y);
            db.z = f2bf(nv.z - cv.z); db.w = f2bf(nv.w - cv.w);
            *(u16x4*)&ed[(g * 9 + q) * 264 + 128 + 4 * j] = db;
        }
    }
    __syncthreads();

    int wv = tid >> 6;
    int lane = tid & 63;
    int quad = lane >> 4, col = lane & 15;

    float b1v = b1[16 * wv + col];
    f32x4 acc[9];
    #pragma unroll
    for (int t = 0; t < 9; ++t) acc[t] = (f32x4){b1v, b1v, b1v, b1v};

    const short8* w1f = (const short8*)wf1;
    #pragma unroll
    for (int kk = 0; kk < 8; ++kk) {
        short8 bf = w1f[(kk * 8 + wv) * 64 + lane];
        #pragma unroll
        for (int t = 0; t < 9; ++t) {
            short8 af = *(const short8*)&ed[(16 * t + col) * 264 + kk * 32 + quad * 8];
            acc[t] = __builtin_amdgcn_mfma_f32_16x16x32_bf16(af, bf, acc[t], 0, 0, 0);
        }
    }
    #pragma unroll
    for (int t = 0; t < 9; ++t)
        #pragma unroll
        for (int r = 0; r < 4; ++r) {
            float v = acc[t][r];
            v = (v >= 0.f) ? v : NEG_SLOPE * v;
            h1[(16 * t + quad * 4 + r) * 136 + 16 * wv + col] = f2bf(v);
        }
    __syncthreads();

    f32x4 acc2[9];
    #pragma unroll
    for (int t = 0; t < 9; ++t) acc2[t] = (f32x4){0.f, 0.f, 0.f, 0.f};

    const short8* w2f = (const short8*)wf2;
    #pragma unroll
    for (int kk = 0; kk < 4; ++kk) {
        short8 bf = w2f[(kk * 8 + wv) * 64 + lane];
        #pragma unroll
        for (int t = 0; t < 9; ++t) {
            short8 af = *(const short8*)&h1[(16 * t + col) * 136 + kk * 32 + quad * 8];
            acc2[t] = __builtin_amdgcn_mfma_f32_16x16x32_bf16(af, bf, acc2[t], 0, 0, 0);
        }
    }
    #pragma unroll
    for (int t = 0; t < 9; ++t)
        #pragma unroll
        for (int r = 0; r < 4; ++r)
            h2[(16 * t + quad * 4 + r) * 132 + 16 * wv + col] = acc2[t][r];
    __syncthreads();

    int p = tid & 15, nbase = tid >> 4;
    #pragma unroll
    for (int it = 0; it < 4; ++it) {
        int n = nbase + 32 * it;
        float m = h2[(p * 9) * 132 + n];
        #pragma unroll
        for (int q = 1; q < 9; ++q)
            m = fmaxf(m, h2[(p * 9 + q) * 132 + n]);
        msg[(b * C_ + n) * N_ + n0 + p] = m + b2[n];
    }
}

// ---------------------------------------------------- BN statistics per channel
__global__ __launch_bounds__(256) void k_bnstats(const float* __restrict__ msg,
        const float* __restrict__ gamma, const float* __restrict__ beta,
        float* __restrict__ scale, float* __restrict__ shift)
{
    int c = blockIdx.x, tid = threadIdx.x;
    float s = 0.f, ss = 0.f;
    for (int b = 0; b < B_; ++b) {
        const float* row = msg + (b * C_ + c) * N_;
        for (int j = tid; j < N_; j += 256) {
            float v = row[j];
            s += v; ss += v * v;
        }
    }
    __shared__ float rs[256], rss[256];
    rs[tid] = s; rss[tid] = ss;
    __syncthreads();
    for (int off = 128; off > 0; off >>= 1) {
        if (tid < off) { rs[tid] += rs[tid + off]; rss[tid] += rss[tid + off]; }
        __syncthreads();
    }
    if (tid == 0) {
        float mean = rs[0] / (float)(B_ * N_);
        float var = rss[0] / (float)(B_ * N_) - mean * mean;
        float inv = 1.0f / sqrtf(var + BN_EPS);
        float g = gamma[c];
        scale[c] = g * inv;
        shift[c] = beta[c] - g * inv * mean;
    }
}

// ------------------------------------------- BN apply + residual + final ReLU
__global__ __launch_bounds__(256) void k_final(const float* __restrict__ msg,
        const float* __restrict__ x, const float* __restrict__ scale,
        const float* __restrict__ shift, float* __restrict__ out)
{
    int i = blockIdx.x * 256 + threadIdx.x;
    int e = i << 2;
    int c = (e >> 10) & 127;
    float sc = scale[c], sh = shift[c];
    float4 m4 = reinterpret_cast<const float4*>(msg)[i];
    float4 x4 = reinterpret_cast<const float4*>(x)[i];
    float4 o;
    o.x = fmaxf(m4.x * sc + sh + x4.x, 0.f);
    o.y = fmaxf(m4.y * sc + sh + x4.y, 0.f);
    o.z = fmaxf(m4.z * sc + sh + x4.z, 0.f);
    o.w = fmaxf(m4.w * sc + sh + x4.w, 0.f);
    reinterpret_cast<float4*>(out)[i] = o;
}

extern "C" void kernel_launch(void* const* d_in, const int* in_sizes, int n_in,
                              void* d_out, int out_size, void* d_ws, size_t ws_size,
                              hipStream_t stream)
{
    const float* x     = (const float*)d_in[0];
    const float* W1    = (const float*)d_in[1];
    const float* b1    = (const float*)d_in[2];
    const float* W2    = (const float*)d_in[3];
    const float* b2    = (const float*)d_in[4];
    const float* gamma = (const float*)d_in[5];
    const float* beta  = (const float*)d_in[6];
    float* out = (float*)d_out;

    float* ws     = (float*)d_ws;
    float* featsT = ws;                     // 8 MB
    float* msg    = ws + 2097152;           // 8 MB; Bf aliases (dead before k_edge)
    unsigned short* Bf = (unsigned short*)(ws + 2097152);
    float* sq     = ws + 4194304;           // 16384
    float* scale  = ws + 4210688;           // 128
    float* shift  = ws + 4210816;           // 128
    int*   idx    = (int*)(ws + 4210944);   // 147456 ints
    unsigned short* wf1 = (unsigned short*)(ws + 4358400);  // 32768 bf16
    unsigned short* wf2 = (unsigned short*)(ws + 4374784);  // 16384 bf16

    k_transpose<<<2048, 256, 0, stream>>>(x, featsT);
    k_prep     <<<2048, 256, 0, stream>>>(featsT, Bf, sq);
    k_prepack  <<<  24, 256, 0, stream>>>(W1, W2, wf1, wf2);
    k_knn      <<<1024, 512, 0, stream>>>(featsT, Bf, sq, idx);
    k_edge     <<<1024, 512, 0, stream>>>(featsT, idx, wf1, wf2, b1, b2, msg);
    k_bnstats  <<< 128, 256, 0, stream>>>(msg, gamma, beta, scale, shift);
    k_final    <<<2048, 256, 0, stream>>>(msg, x, scale, shift, out);
}

// Round 7
// 205.212 us; speedup vs baseline: 4.7890x; 1.0559x over previous
//
#include <hip/hip_runtime.h>

#define B_ 16
#define C_ 128
#define N_ 1024
#define K_ 9
#define NEG_SLOPE 0.2f
#define BN_EPS 1e-5f
#define FLT_BIG 3.402823466e38f

typedef __attribute__((ext_vector_type(8))) short short8;
typedef __attribute__((ext_vector_type(4))) float f32x4;
typedef __attribute__((ext_vector_type(4))) unsigned short u16x4;

__device__ __forceinline__ unsigned short f2bf(float f) {
    union { float f; unsigned u; } v; v.f = f;
    unsigned r = v.u + 0x7fffu + ((v.u >> 16) & 1u);   // RNE
    return (unsigned short)(r >> 16);
}
__device__ __forceinline__ float bf2f(unsigned short h) {
    union { unsigned u; float f; } v; v.u = ((unsigned)h) << 16; return v.f;
}

// ------------------------------------------------- featsT[b][n][c] = x[b][c][n]
__global__ __launch_bounds__(256) void k_transpose(const float* __restrict__ x,
                                                   float* __restrict__ featsT)
{
    __shared__ float t[32][33];
    int blk = blockIdx.x;            // B * (C/32) * (N/32) = 2048
    int b = blk / 128;
    int rem = blk % 128;
    int c0 = (rem / 32) * 32;
    int n0 = (rem % 32) * 32;
    int tj = threadIdx.x & 31;
    int ti = threadIdx.x >> 5;
    #pragma unroll
    for (int s = 0; s < 32; s += 8)
        t[ti + s][tj] = x[(b * C_ + c0 + ti + s) * N_ + n0 + tj];
    __syncthreads();
    #pragma unroll
    for (int s = 0; s < 32; s += 8)
        featsT[(b * N_ + n0 + ti + s) * C_ + c0 + tj] = t[tj][ti + s];
}

// ---------------- prep: Bf (B-frag hi/lo bf16 for KNN MFMA) + sq (fp32)
__global__ __launch_bounds__(256) void k_prep(const float* __restrict__ featsT,
        unsigned short* __restrict__ Bf, float* __restrict__ sq)
{
    int tid = threadIdx.x;
    int lane = tid & 63, wv = tid >> 6;
    int half = lane >> 5;
    int l2 = lane & 31;
    int gp = blockIdx.x * 8 + wv * 2 + half; // global point
    int b = gp >> 10, n = gp & 1023;

    int ch0 = (l2 & 15) * 8;
    const float4* f4 = (const float4*)&featsT[gp * C_ + ch0];
    float4 v0 = f4[0], v1 = f4[1];

    u16x4 o0, o1;
    if (l2 < 16) {
        o0.x = f2bf(v0.x); o0.y = f2bf(v0.y); o0.z = f2bf(v0.z); o0.w = f2bf(v0.w);
        o1.x = f2bf(v1.x); o1.y = f2bf(v1.y); o1.z = f2bf(v1.z); o1.w = f2bf(v1.w);
    } else {
        o0.x = f2bf(v0.x - bf2f(f2bf(v0.x))); o0.y = f2bf(v0.y - bf2f(f2bf(v0.y)));
        o0.z = f2bf(v0.z - bf2f(f2bf(v0.z))); o0.w = f2bf(v0.w - bf2f(f2bf(v0.w)));
        o1.x = f2bf(v1.x - bf2f(f2bf(v1.x))); o1.y = f2bf(v1.y - bf2f(f2bf(v1.y)));
        o1.z = f2bf(v1.z - bf2f(f2bf(v1.z))); o1.w = f2bf(v1.w - bf2f(f2bf(v1.w)));
    }
    // chunk = ((b*8 + kb)*64 + tile)*64 + quad*16 + (n&15); kb 0..3 hi, 4..7 lo
    long chunk = (((long)(b * 8 + (l2 >> 2)) * 64 + (n >> 4)) << 6) + ((l2 & 3) * 16 + (n & 15));
    *(u16x4*)&Bf[chunk * 8]     = o0;
    *(u16x4*)&Bf[chunk * 8 + 4] = o1;

    float ss = v0.x*v0.x + v0.y*v0.y + v0.z*v0.z + v0.w*v0.w
             + v1.x*v1.x + v1.y*v1.y + v1.z*v1.z + v1.w*v1.w;
    #pragma unroll
    for (int off = 1; off < 16; off <<= 1)
        ss += __shfl_xor(ss, off);
    if (l2 == 0) sq[gp] = ss;
}

// --------------- MFMA KNN: 16 rows x 1024 cols; exact-key top-9 selection
__global__ __launch_bounds__(512, 2) void k_knn(const float* __restrict__ featsT,
        const unsigned short* __restrict__ Bf, const float* __restrict__ sq,
        int* __restrict__ idxout)
{
    __shared__ unsigned short Ahl[16][264];   // [row][hi 0..127 | lo 128..255]
    __shared__ unsigned keybuf[16][1028];     // full monotone u32 keys (exact order)
    __shared__ float sqn[16];

    int L = blockIdx.x;                       // 1024 = 16 b * 64 tiles
    int xcd = L & 7, slot = L >> 3;
    int b = xcd * 2 + (slot >> 6);
    int tile = slot & 63;
    int n0 = tile * 16;
    int tid = threadIdx.x;

    {   // stage A tile, split hi/lo
        int row = tid >> 5, c4 = (tid & 31) * 4;
        float4 v = *(const float4*)&featsT[(b * N_ + n0 + row) * C_ + c4];
        u16x4 hi, lo;
        hi.x = f2bf(v.x); lo.x = f2bf(v.x - bf2f(hi.x));
        hi.y = f2bf(v.y); lo.y = f2bf(v.y - bf2f(hi.y));
        hi.z = f2bf(v.z); lo.z = f2bf(v.z - bf2f(hi.z));
        hi.w = f2bf(v.w); lo.w = f2bf(v.w - bf2f(hi.w));
        *(u16x4*)&Ahl[row][c4] = hi;
        *(u16x4*)&Ahl[row][128 + c4] = lo;
    }
    if (tid < 16) sqn[tid] = sq[b * N_ + n0 + tid];
    __syncthreads();

    int wv = tid >> 6, lane = tid & 63, quad = lane >> 4, cl = lane & 15;

    f32x4 acc[8];
    #pragma unroll
    for (int t = 0; t < 8; ++t) acc[t] = (f32x4){0.f, 0.f, 0.f, 0.f};

    const short8* bfp = (const short8*)Bf;
    // B-hi passes: each B chunk feeds hiA*hiB and loA*hiB (read B once)
    #pragma unroll
    for (int kb = 0; kb < 4; ++kb) {
        short8 afh = *(const short8*)&Ahl[cl][kb * 32 + quad * 8];
        short8 afl = *(const short8*)&Ahl[cl][128 + kb * 32 + quad * 8];
        long base = (((long)(b * 8 + kb) * 64 + wv * 8) << 6) + lane;
        #pragma unroll
        for (int t = 0; t < 8; ++t) {
            short8 bfr = bfp[base + t * 64];
            acc[t] = __builtin_amdgcn_mfma_f32_16x16x32_bf16(afh, bfr, acc[t], 0, 0, 0);
            acc[t] = __builtin_amdgcn_mfma_f32_16x16x32_bf16(afl, bfr, acc[t], 0, 0, 0);
        }
    }
    // B-lo passes: hiA*loB
    #pragma unroll
    for (int kb = 4; kb < 8; ++kb) {
        short8 afh = *(const short8*)&Ahl[cl][(kb - 4) * 32 + quad * 8];
        long base = (((long)(b * 8 + kb) * 64 + wv * 8) << 6) + lane;
        #pragma unroll
        for (int t = 0; t < 8; ++t) {
            short8 bfr = bfp[base + t * 64];
            acc[t] = __builtin_amdgcn_mfma_f32_16x16x32_bf16(afh, bfr, acc[t], 0, 0, 0);
        }
    }

    // d2 = sq[n] + sq[m] - 2*dot -> full-precision monotone u32 key
    #pragma unroll
    for (int t = 0; t < 8; ++t) {
        int col = ((wv * 8 + t) << 4) + cl;
        float sm = sq[b * N_ + col];
        #pragma unroll
        for (int r = 0; r < 4; ++r) {
            float d2 = fmaf(-2.f, acc[t][r], sm + sqn[quad * 4 + r]);
            unsigned bits = __float_as_uint(d2);
            keybuf[quad * 4 + r][col] = bits ^ ((unsigned)((int)bits >> 31) | 0x80000000u);
        }
    }
    __syncthreads();

    // top-9 per row: wave wv owns rows 2wv, 2wv+1; lane j-slot col = lane + 64*j
    #pragma unroll 1
    for (int rr = 0; rr < 2; ++rr) {
        int row = wv * 2 + rr;
        unsigned v[16];
        #pragma unroll
        for (int j = 0; j < 16; ++j)
            v[j] = keybuf[row][lane + (j << 6)];   // stride-1: conflict-free

        unsigned m = v[0]; int bj = 0;
        #pragma unroll
        for (int j = 1; j < 16; ++j)
            if (v[j] < m) { m = v[j]; bj = j; }

        #pragma unroll 1
        for (int q = 0; q < K_; ++q) {
            unsigned d = m;
            #pragma unroll
            for (int off = 1; off < 64; off <<= 1)
                d = min(d, (unsigned)__shfl_xor((int)d, off));
            // smallest col among lanes holding d (exact lex tie-break)
            unsigned cmin = (m == d) ? (unsigned)(lane + (bj << 6)) : 0xFFFFFFFFu;
            unsigned c = cmin;
            #pragma unroll
            for (int off = 1; off < 64; off <<= 1)
                c = min(c, (unsigned)__shfl_xor((int)c, off));
            if (lane == 0)
                idxout[(b * N_ + n0 + row) * K_ + q] = (int)c;
            if (q < K_ - 1 && cmin == c) {         // unique winner: mask + rescan
                v[bj] = 0xFFFFFFFFu;
                m = v[0]; bj = 0;
                #pragma unroll
                for (int j = 1; j < 16; ++j)
                    if (v[j] < m) { m = v[j]; bj = j; }
            }
        }
    }
}

// ----------------------- prepack W1/W2 into MFMA B-fragment order (bf16)
__global__ __launch_bounds__(256) void k_prepack(const float* __restrict__ W1,
        const float* __restrict__ W2, unsigned short* __restrict__ wf1,
        unsigned short* __restrict__ wf2)
{
    int t = blockIdx.x * 256 + threadIdx.x;       // 6144 threads
    if (t < 4096) {                               // W1: kk 0..7
        int kk = t >> 9, w = (t >> 6) & 7, lane = t & 63;
        int quad = lane >> 4, col = lane & 15;
        #pragma unroll
        for (int j = 0; j < 8; ++j)
            wf1[t * 8 + j] = f2bf(W1[(kk * 32 + quad * 8 + j) * C_ + 16 * w + col]);
    } else if (t < 6144) {                        // W2: kk 0..3
        int t2 = t - 4096;
        int kk = t2 >> 9, w = (t2 >> 6) & 7, lane = t2 & 63;
        int quad = lane >> 4, col = lane & 15;
        #pragma unroll
        for (int j = 0; j < 8; ++j)
            wf2[t2 * 8 + j] = f2bf(W2[(kk * 32 + quad * 8 + j) * C_ + 16 * w + col]);
    }
}

// ------------------- MFMA edge-MLP + maxpool: block = 16 points (144 edge rows)
__global__ __launch_bounds__(512, 1) void k_edge(const float* __restrict__ featsT,
        const int* __restrict__ idx, const unsigned short* __restrict__ wf1,
        const unsigned short* __restrict__ wf2, const float* __restrict__ b1,
        const float* __restrict__ b2, float* __restrict__ msg)
{
    __shared__ __align__(16) char smem[76032 + 39168];
    unsigned short* ed = (unsigned short*)smem;     // [144][264] bf16
    float*          h2 = (float*)smem;              // [144][132] fp32 (aliases ed)
    unsigned short* h1 = (unsigned short*)(smem + 76032);  // [144][136] bf16
    __shared__ int nb[144];

    int blk = blockIdx.x;                 // 1024 = 16 b * 64 tiles
    int b = blk >> 6;
    int n0 = (blk & 63) * 16;
    int tid = threadIdx.x;

    if (tid < 144) nb[tid] = idx[(b * N_ + n0 + tid / 9) * K_ + tid % 9];
    __syncthreads();

    {
        int g = tid >> 5, j = tid & 31;
        const float4* fT4 = (const float4*)featsT;
        float4 cv = fT4[(b * N_ + n0 + g) * 32 + j];
        u16x4 cb; cb.x = f2bf(cv.x); cb.y = f2bf(cv.y);
        cb.z = f2bf(cv.z); cb.w = f2bf(cv.w);
        #pragma unroll
        for (int q = 0; q < 9; ++q)
            *(u16x4*)&ed[(g * 9 + q) * 264 + 4 * j] = cb;
        #pragma unroll
        for (int q = 0; q < 9; ++q) {
            float4 nv = fT4[(b * N_ + nb[g * 9 + q]) * 32 + j];
            u16x4 db;
            db.x = f2bf(nv.x - cv.x); db.y = f2bf(nv.y - cv.y);
            db.z = f2bf(nv.z - cv.z); db.w = f2bf(nv.w - cv.w);
            *(u16x4*)&ed[(g * 9 + q) * 264 + 128 + 4 * j] = db;
        }
    }
    __syncthreads();

    int wv = tid >> 6;
    int lane = tid & 63;
    int quad = lane >> 4, col = lane & 15;

    float b1v = b1[16 * wv + col];
    f32x4 acc[9];
    #pragma unroll
    for (int t = 0; t < 9; ++t) acc[t] = (f32x4){b1v, b1v, b1v, b1v};

    const short8* w1f = (const short8*)wf1;
    #pragma unroll
    for (int kk = 0; kk < 8; ++kk) {
        short8 bf = w1f[(kk * 8 + wv) * 64 + lane];
        #pragma unroll
        for (int t = 0; t < 9; ++t) {
            short8 af = *(const short8*)&ed[(16 * t + col) * 264 + kk * 32 + quad * 8];
            acc[t] = __builtin_amdgcn_mfma_f32_16x16x32_bf16(af, bf, acc[t], 0, 0, 0);
        }
    }
    #pragma unroll
    for (int t = 0; t < 9; ++t)
        #pragma unroll
        for (int r = 0; r < 4; ++r) {
            float v = acc[t][r];
            v = (v >= 0.f) ? v : NEG_SLOPE * v;
            h1[(16 * t + quad * 4 + r) * 136 + 16 * wv + col] = f2bf(v);
        }
    __syncthreads();

    f32x4 acc2[9];
    #pragma unroll
    for (int t = 0; t < 9; ++t) acc2[t] = (f32x4){0.f, 0.f, 0.f, 0.f};

    const short8* w2f = (const short8*)wf2;
    #pragma unroll
    for (int kk = 0; kk < 4; ++kk) {
        short8 bf = w2f[(kk * 8 + wv) * 64 + lane];
        #pragma unroll
        for (int t = 0; t < 9; ++t) {
            short8 af = *(const short8*)&h1[(16 * t + col) * 136 + kk * 32 + quad * 8];
            acc2[t] = __builtin_amdgcn_mfma_f32_16x16x32_bf16(af, bf, acc2[t], 0, 0, 0);
        }
    }
    #pragma unroll
    for (int t = 0; t < 9; ++t)
        #pragma unroll
        for (int r = 0; r < 4; ++r)
            h2[(16 * t + quad * 4 + r) * 132 + 16 * wv + col] = acc2[t][r];
    __syncthreads();

    int p = tid & 15, nbase = tid >> 4;
    #pragma unroll
    for (int it = 0; it < 4; ++it) {
        int n = nbase + 32 * it;
        float m = h2[(p * 9) * 132 + n];
        #pragma unroll
        for (int q = 1; q < 9; ++q)
            m = fmaxf(m, h2[(p * 9 + q) * 132 + n]);
        msg[(b * C_ + n) * N_ + n0 + p] = m + b2[n];
    }
}

// ---------------------------------------------------- BN statistics per channel
__global__ __launch_bounds__(256) void k_bnstats(const float* __restrict__ msg,
        const float* __restrict__ gamma, const float* __restrict__ beta,
        float* __restrict__ scale, float* __restrict__ shift)
{
    int c = blockIdx.x, tid = threadIdx.x;
    float s = 0.f, ss = 0.f;
    for (int b = 0; b < B_; ++b) {
        const float* row = msg + (b * C_ + c) * N_;
        for (int j = tid; j < N_; j += 256) {
            float v = row[j];
            s += v; ss += v * v;
        }
    }
    __shared__ float rs[256], rss[256];
    rs[tid] = s; rss[tid] = ss;
    __syncthreads();
    for (int off = 128; off > 0; off >>= 1) {
        if (tid < off) { rs[tid] += rs[tid + off]; rss[tid] += rss[tid + off]; }
        __syncthreads();
    }
    if (tid == 0) {
        float mean = rs[0] / (float)(B_ * N_);
        float var = rss[0] / (float)(B_ * N_) - mean * mean;
        float inv = 1.0f / sqrtf(var + BN_EPS);
        float g = gamma[c];
        scale[c] = g * inv;
        shift[c] = beta[c] - g * inv * mean;
    }
}

// ------------------------------------------- BN apply + residual + final ReLU
__global__ __launch_bounds__(256) void k_final(const float* __restrict__ msg,
        const float* __restrict__ x, const float* __restrict__ scale,
        const float* __restrict__ shift, float* __restrict__ out)
{
    int i = blockIdx.x * 256 + threadIdx.x;
    int e = i << 2;
    int c = (e >> 10) & 127;
    float sc = scale[c], sh = shift[c];
    float4 m4 = reinterpret_cast<const float4*>(msg)[i];
    float4 x4 = reinterpret_cast<const float4*>(x)[i];
    float4 o;
    o.x = fmaxf(m4.x * sc + sh + x4.x, 0.f);
    o.y = fmaxf(m4.y * sc + sh + x4.y, 0.f);
    o.z = fmaxf(m4.z * sc + sh + x4.z, 0.f);
    o.w = fmaxf(m4.w * sc + sh + x4.w, 0.f);
    reinterpret_cast<float4*>(out)[i] = o;
}

extern "C" void kernel_launch(void* const* d_in, const int* in_sizes, int n_in,
                              void* d_out, int out_size, void* d_ws, size_t ws_size,
                              hipStream_t stream)
{
    const float* x     = (const float*)d_in[0];
    const float* W1    = (const float*)d_in[1];
    const float* b1    = (const float*)d_in[2];
    const float* W2    = (const float*)d_in[3];
    const float* b2    = (const float*)d_in[4];
    const float* gamma = (const float*)d_in[5];
    const float* beta  = (const float*)d_in[6];
    float* out = (float*)d_out;

    float* ws     = (float*)d_ws;
    float* featsT = ws;                     // 8 MB
    float* msg    = ws + 2097152;           // 8 MB; Bf aliases (dead before k_edge)
    unsigned short* Bf = (unsigned short*)(ws + 2097152);
    float* sq     = ws + 4194304;           // 16384
    float* scale  = ws + 4210688;           // 128
    float* shift  = ws + 4210816;           // 128
    int*   idx    = (int*)(ws + 4210944);   // 147456 ints
    unsigned short* wf1 = (unsigned short*)(ws + 4358400);  // 32768 bf16
    unsigned short* wf2 = (unsigned short*)(ws + 4374784);  // 16384 bf16

    k_transpose<<<2048, 256, 0, stream>>>(x, featsT);
    k_prep     <<<2048, 256, 0, stream>>>(featsT, Bf, sq);
    k_prepack  <<<  24, 256, 0, stream>>>(W1, W2, wf1, wf2);
    k_knn      <<<1024, 512, 0, stream>>>(featsT, Bf, sq, idx);
    k_edge     <<<1024, 512, 0, stream>>>(featsT, idx, wf1, wf2, b1, b2, msg);
    k_bnstats  <<< 128, 256, 0, stream>>>(msg, gamma, beta, scale, shift);
    k_final    <<<2048, 256, 0, stream>>>(msg, x, scale, shift, out);
}